// Round 9
// baseline (3164.764 us; speedup 1.0000x reference)
//
#include <hip/hip_runtime.h>
#include <math.h>

#define B_SZ 2
#define T_SEQ 2048
#define D_MODEL 2048
#define NHEAD 16
#define HDIM 128
#define FFN 8192
#define NTOK (B_SZ*T_SEQ)   // 4096

// d_out layout (fp32): x_posterior | tpn_loss | causal_loss | g | binary | probs
#define OFF_TPN 8388608
#define OFF_CL  8388609
#define OFF_G   8388610
#define OFF_B   8392706
#define OFF_CP  8396802

#define RLO 1024.0f
#define RLOI 9.765625e-4f   // 1/1024

typedef __attribute__((ext_vector_type(8))) _Float16 f16x8;
typedef __attribute__((ext_vector_type(4))) float f32x4;
typedef unsigned int u32;
typedef const u32 __attribute__((address_space(1)))* gas_p;
typedef u32 __attribute__((address_space(3)))* las_p;

__device__ __forceinline__ void gload16(const _Float16* g, _Float16* l) {
  __builtin_amdgcn_global_load_lds((gas_p)g, (las_p)l, 16, 0, 0);
}
__device__ __forceinline__ f16x8 ld8h(const _Float16* p) {
  return *reinterpret_cast<const f16x8*>(p);
}
__device__ __forceinline__ f32x4 mfma16h(f16x8 a, f16x8 b, f32x4 c) {
  return __builtin_amdgcn_mfma_f32_16x16x32_f16(a, b, c, 0, 0, 0);
}
__device__ __forceinline__ f32x4 zero4() { f32x4 z = {0.f,0.f,0.f,0.f}; return z; }
__device__ __forceinline__ float wredsum(float v) {
  #pragma unroll
  for (int d = 1; d < 64; d <<= 1) v += __shfl_xor(v, d, 64);
  return v;
}
__device__ __forceinline__ void split1(float v, _Float16& h, _Float16& l) {
  _Float16 hh = (_Float16)v;
  h = hh;
  l = (_Float16)((v - (float)hh) * RLO);
}

// ---- weight sub-panel transpose + fp16 split ----
// dst[c][r] (c<C, r<R, dst row stride R) = split(src[(r0+r)*srcStride + c0+c])
__global__ __launch_bounds__(256) void wsplit_kernel(const float* __restrict__ src,
                                                     _Float16* __restrict__ dhi,
                                                     _Float16* __restrict__ dlo,
                                                     int srcStride, int r0, int c0,
                                                     int R) {
  __shared__ float tile[32][33];
  int cb = blockIdx.x * 32, rb = blockIdx.y * 32;
  int tx = threadIdx.x, ty = threadIdx.y;
  #pragma unroll
  for (int i = 0; i < 4; ++i)
    tile[ty + i*8][tx] = src[(size_t)(r0 + rb + ty + i*8) * srcStride + c0 + cb + tx];
  __syncthreads();
  #pragma unroll
  for (int i = 0; i < 4; ++i) {
    float v = tile[tx][ty + i*8];
    _Float16 h, l; split1(v, h, l);
    size_t idx = (size_t)(cb + ty + i*8) * R + rb + tx;
    dhi[idx] = h; dlo[idx] = l;
  }
}

// ---- RMSNorm: fp32 in -> f16 pair out ----
__global__ __launch_bounds__(256) void rmsnorm_kernel(const float* __restrict__ x,
                                                      const float* __restrict__ wgt,
                                                      _Float16* __restrict__ oh,
                                                      _Float16* __restrict__ ol) {
  const int row = blockIdx.x, tid = threadIdx.x;
  const float* xr = x + (size_t)row * D_MODEL;
  float4 v0 = *(const float4*)(xr + tid*8);
  float4 v1 = *(const float4*)(xr + tid*8 + 4);
  float ss = v0.x*v0.x + v0.y*v0.y + v0.z*v0.z + v0.w*v0.w
           + v1.x*v1.x + v1.y*v1.y + v1.z*v1.z + v1.w*v1.w;
  ss = wredsum(ss);
  __shared__ float red[4];
  if ((tid & 63) == 0) red[tid >> 6] = ss;
  __syncthreads();
  float tot = red[0] + red[1] + red[2] + red[3];
  float inv = 1.f / sqrtf(tot / (float)D_MODEL + 1e-6f);
  float4 w0 = *(const float4*)(wgt + tid*8);
  float4 w1 = *(const float4*)(wgt + tid*8 + 4);
  float f[8];
  f[0]=v0.x*inv*w0.x; f[1]=v0.y*inv*w0.y; f[2]=v0.z*inv*w0.z; f[3]=v0.w*inv*w0.w;
  f[4]=v1.x*inv*w1.x; f[5]=v1.y*inv*w1.y; f[6]=v1.z*inv*w1.z; f[7]=v1.w*inv*w1.w;
  f16x8 hh, ll;
  #pragma unroll
  for (int i = 0; i < 8; ++i) { _Float16 h, l; split1(f[i], h, l); hh[i]=h; ll[i]=l; }
  *(f16x8*)(oh + (size_t)row * D_MODEL + tid*8) = hh;
  *(f16x8*)(ol + (size_t)row * D_MODEL + tid*8) = ll;
}

// ---- all-pair GEMM: C[M][N] = (Ah+Al/1024)[M][K] @ (Bh+Bl/1024)[N][K]^T ----
// 128x128 tile, BK=32, 4 waves 2x2, 3x mfma_f32_16x16x32_f16 per frag pair.
// Double-buffered LDS (64 KiB) + cross-step prefetch (T3-minimum).
// Tile order: grouped (GROUP_M=8) then XCD-chunked -> supertile L2 reuse.
// Staging: global_load_lds width-16, 16B chunks XOR-swizzled on BOTH sides.
// MODE: 0 plain, 1 +bias, 2 silu(v+bias), 3 +resid, 4 silu(g)*v (g pair)
// QKV: blockIdx.z selects Q/K/V; V is written TRANSPOSED to [b*h][d][T].
template<int MODE, bool OUT_SPLIT, bool QKV>
__global__ __launch_bounds__(256) void gemm2_kernel(
    const _Float16* __restrict__ Ahi, const _Float16* __restrict__ Alo,
    const _Float16* __restrict__ Bhi, const _Float16* __restrict__ Blo,
    const float* __restrict__ b0, const float* __restrict__ b1,
    const float* __restrict__ b2, const float* __restrict__ resid,
    const _Float16* __restrict__ ghi, const _Float16* __restrict__ glo,
    void* __restrict__ C1, void* __restrict__ C2,
    int M, int N, int K) {
  // grouped + XCD-chunked tile order (nbm always a multiple of 8 here)
  const int nbn = gridDim.x, nbm = gridDim.y;
  int bid = blockIdx.y * nbn + blockIdx.x;
  bid = (bid & 7) * ((nbn * nbm) >> 3) + (bid >> 3);   // XCD chunking
  const int nig = nbn << 3;
  const int gid = bid / nig, rem = bid - gid * nig;
  const int by = (gid << 3) + (rem & 7);
  const int bx = rem >> 3;
  int sel = 0;
  const float* bias = b0;
  size_t cbase = 0, bwoff = 0;
  if (QKV) {
    sel = blockIdx.z;
    bias = (sel == 0) ? b0 : ((sel == 1) ? b1 : b2);
    bwoff = (size_t)sel * D_MODEL * D_MODEL;
    cbase = (size_t)sel * (size_t)NTOK * D_MODEL;
  }
  const int n0 = bx * 128, m0 = by * 128;
  const int tid = threadIdx.x, lane = tid & 63, wv = tid >> 6;
  const int wr = wv >> 1, wc = wv & 1;
  const int l16 = lane & 15, lg = lane >> 4;
  // [buf][arr][128][32] halves; arr: 0=Ah 1=Al 2=Bh 3=Bl
  __shared__ _Float16 SH[2 * 4 * 128 * 32];
  f32x4 acc1[4][4], acc2[4][4];
  #pragma unroll
  for (int i = 0; i < 4; ++i)
    #pragma unroll
    for (int j = 0; j < 4; ++j) { acc1[i][j] = zero4(); acc2[i][j] = zero4(); }
  // staging: wave wv covers rows [wv*32, wv*32+32); 2 issues of 16 rows/array.
  const int srow = wv * 32 + (lane >> 2);
  const int scol = ((lane & 3) ^ ((lane >> 2) & 3)) * 8;
  const _Float16* ga0  = Ahi + (size_t)(m0 + srow) * K + scol;
  const _Float16* ga1  = ga0 + (size_t)16 * K;
  const _Float16* gal0 = Alo + (size_t)(m0 + srow) * K + scol;
  const _Float16* gal1 = gal0 + (size_t)16 * K;
  const _Float16* gb0  = Bhi + bwoff + (size_t)(n0 + srow) * K + scol;
  const _Float16* gb1  = gb0 + (size_t)16 * K;
  const _Float16* gbl0 = Blo + bwoff + (size_t)(n0 + srow) * K + scol;
  const _Float16* gbl1 = gbl0 + (size_t)16 * K;
  const int dbase = wv * 32 * 32;          // element offset within array
  const int csw = (lg ^ (l16 & 3)) * 8;    // swizzled read chunk offset

  #define STAGE(buf, kk) do {                                   \
    _Float16* sb = SH + (buf) * 16384;                          \
    gload16(ga0  + (kk), sb          + dbase);                  \
    gload16(ga1  + (kk), sb          + dbase + 512);            \
    gload16(gal0 + (kk), sb + 4096  + dbase);                   \
    gload16(gal1 + (kk), sb + 4096  + dbase + 512);             \
    gload16(gb0  + (kk), sb + 8192  + dbase);                   \
    gload16(gb1  + (kk), sb + 8192  + dbase + 512);             \
    gload16(gbl0 + (kk), sb + 12288 + dbase);                   \
    gload16(gbl1 + (kk), sb + 12288 + dbase + 512);             \
  } while (0)

  int cur = 0;
  STAGE(0, 0);
  __syncthreads();
  for (int kk = 0; kk < K; kk += 32) {
    if (kk + 32 < K) STAGE(cur ^ 1, kk + 32);   // prefetch next step
    const _Float16* sb = SH + cur * 16384;
    f16x8 af_h[4], af_l[4];
    #pragma unroll
    for (int i = 0; i < 4; ++i) {
      const int off = (wr*64 + i*16 + l16) * 32 + csw;
      af_h[i] = ld8h(sb + off);
      af_l[i] = ld8h(sb + 4096 + off);
    }
    #pragma unroll
    for (int j = 0; j < 4; ++j) {
      const int offb = (wc*64 + j*16 + l16) * 32 + csw;
      f16x8 bh = ld8h(sb + 8192 + offb);
      f16x8 bl = ld8h(sb + 12288 + offb);
      #pragma unroll
      for (int i = 0; i < 4; ++i) {
        acc1[i][j] = mfma16h(af_h[i], bh, acc1[i][j]);
        acc2[i][j] = mfma16h(af_h[i], bl, acc2[i][j]);
        acc2[i][j] = mfma16h(af_l[i], bh, acc2[i][j]);
      }
    }
    __syncthreads();   // drains prefetch vmcnt + publishes buf^1
    cur ^= 1;
  }
  #undef STAGE
  #pragma unroll
  for (int i = 0; i < 4; ++i) {
    const int row0 = m0 + wr*64 + i*16 + lg*4;   // D: row=(lane>>4)*4+t, col=lane&15
    #pragma unroll
    for (int j = 0; j < 4; ++j) {
      const int col = n0 + wc*64 + j*16 + l16;
      float bv = (MODE == 1 || MODE == 2) ? bias[col] : 0.f;
      #pragma unroll
      for (int t = 0; t < 4; ++t) {
        const int row = row0 + t;
        size_t idx;
        if (QKV && sel == 2)   // V -> transposed [b*h][d][T] layout
          idx = cbase + (size_t)(row >> 11) * ((size_t)D_MODEL * T_SEQ)
                      + (size_t)col * T_SEQ + (row & (T_SEQ - 1));
        else
          idx = cbase + (size_t)row * N + col;
        float v = acc1[i][j][t] + acc2[i][j][t] * RLOI + bv;
        if (MODE == 2) v = v / (1.f + __expf(-v));
        if (MODE == 3) v += resid[idx];
        if (MODE == 4) {
          float g = (float)ghi[idx] + (float)glo[idx] * RLOI;
          v = g / (1.f + __expf(-g)) * v;
        }
        if (OUT_SPLIT) {
          _Float16 h, l; split1(v, h, l);
          ((_Float16*)C1)[idx] = h;
          ((_Float16*)C2)[idx] = l;
        } else {
          ((float*)C1)[idx] = v;
        }
      }
    }
  }
}

// ---- RoPE (neox), in place on f16 pairs; one token-row per block ----
__global__ __launch_bounds__(256) void rope_kernel(_Float16* __restrict__ Qh,
                                                   _Float16* __restrict__ Ql,
                                                   _Float16* __restrict__ Kh,
                                                   _Float16* __restrict__ Kl) {
  const int row = blockIdx.x;
  const int tpos = row & (T_SEQ - 1);
  __shared__ float svs[64], cvs[64];
  if (threadIdx.x < 64) {
    double invf = exp(-(double)threadIdx.x * (9.210340371976184 / 64.0));
    double ph = fmod((double)tpos * invf, 6.283185307179586476925);
    sincosf((float)ph, &svs[threadIdx.x], &cvs[threadIdx.x]);
  }
  __syncthreads();
  for (int item = threadIdx.x; item < NHEAD * 64; item += 256) {
    const int h = item >> 6, d = item & 63;
    const float sv = svs[d], cv = cvs[d];
    const size_t i0 = (size_t)row * D_MODEL + h*HDIM + d;
    const size_t i1 = i0 + 64;
    float q0 = (float)Qh[i0] + (float)Ql[i0]*RLOI;
    float q1 = (float)Qh[i1] + (float)Ql[i1]*RLOI;
    float k0 = (float)Kh[i0] + (float)Kl[i0]*RLOI;
    float k1 = (float)Kh[i1] + (float)Kl[i1]*RLOI;
    _Float16 hh, ll;
    split1(q0*cv - q1*sv, hh, ll); Qh[i0]=hh; Ql[i0]=ll;
    split1(q1*cv + q0*sv, hh, ll); Qh[i1]=hh; Ql[i1]=ll;
    split1(k0*cv - k1*sv, hh, ll); Kh[i0]=hh; Kl[i0]=ll;
    split1(k1*cv + k0*sv, hh, ll); Kh[i1]=hh; Kl[i1]=ll;
  }
}

// ---- flash attention on pairs: 64 q-rows/block, KV tiles of 32 ----
// K staged via global_load_lds into [32][128] with chunk^(row&7) XOR swizzle
// (applied on global source + ds_read side). V comes pre-transposed from the
// QKV GEMM ([b*h][d][T]) and stages reg->ds_write_b128 into PADDED [128][40]
// (write banks ~2-way, read banks exactly 2-way = free). 46KB LDS, 3 blk/CU.
__global__ __launch_bounds__(256) void attn_kernel(
    const _Float16* __restrict__ Qh, const _Float16* __restrict__ Ql,
    const _Float16* __restrict__ Kh, const _Float16* __restrict__ Kl,
    const _Float16* __restrict__ VTh, const _Float16* __restrict__ VTl,
    _Float16* __restrict__ Oh, _Float16* __restrict__ Ol) {
  const int qb = (int)gridDim.x - 1 - (int)blockIdx.x;  // heavy blocks first
  const int bhid = blockIdx.y;
  const int b = bhid >> 4, h = bhid & 15;
  const int tid = threadIdx.x, lane = tid & 63, w = tid >> 6;
  const int l16 = lane & 15, lg = lane >> 4;
  __shared__ _Float16 Ksh[32][128], Ksl[32][128];   // src-swizzled, DMA
  __shared__ _Float16 Vth[128][40], Vtl[128][40];   // padded, reg->ds_write
  __shared__ _Float16 Psh[4][16][40], Psl[4][16][40];
  const size_t hbase  = (size_t)b * T_SEQ * D_MODEL + (size_t)h * HDIM;
  const size_t vtbase = (size_t)bhid * (size_t)HDIM * T_SEQ;
  const size_t qrow0 = (size_t)qb * 64;

  f16x8 qf_h[4], qf_l[4];
  {
    const size_t qoff = hbase + (qrow0 + w*16 + l16) * D_MODEL + lg*8;
    #pragma unroll
    for (int c = 0; c < 4; ++c) {
      qf_h[c] = ld8h(Qh + qoff + c*32);
      qf_l[c] = ld8h(Ql + qoff + c*32);
    }
  }
  f32x4 acc1[8], acc2[8];
  #pragma unroll
  for (int df = 0; df < 8; ++df) { acc1[df] = zero4(); acc2[df] = zero4(); }
  float mrow[4] = {-3e38f,-3e38f,-3e38f,-3e38f};
  float drow[4] = {0.f,0.f,0.f,0.f};

  // K DMA pointers (source chunk-XOR-swizzled)
  const int krow = w*8 + (lane >> 4);
  const int kch0 = ((lane & 15) ^ (krow & 7)) * 8;
  const int kch1 = ((lane & 15) ^ ((krow + 4) & 7)) * 8;
  const _Float16* gkh0 = Kh + hbase + (size_t)krow * D_MODEL + kch0;
  const _Float16* gkh1 = Kh + hbase + (size_t)(krow + 4) * D_MODEL + kch1;
  const _Float16* gkl0 = Kl + hbase + (size_t)krow * D_MODEL + kch0;
  const _Float16* gkl1 = Kl + hbase + (size_t)(krow + 4) * D_MODEL + kch1;
  _Float16* dkh0 = &Ksh[w*8][0];   _Float16* dkh1 = &Ksh[w*8+4][0];
  _Float16* dkl0 = &Ksl[w*8][0];   _Float16* dkl1 = &Ksl[w*8+4][0];
  // V reg-load pointers (V^T global: [d][T], coalesced 64B per 4 lanes)
  const int vrow = w*32 + (lane >> 2);
  const int vcol = (lane & 3) * 8;
  const _Float16* gvh = VTh + vtbase + (size_t)vrow * T_SEQ + vcol;
  const _Float16* gvl = VTl + vtbase + (size_t)vrow * T_SEQ + vcol;

  const int nkb = (qb + 1) * 2;
  const float scale = 0.088388347648318447f;  // 1/sqrt(128)

  for (int kb = 0; kb < nkb; ++kb) {
    __syncthreads();
    const size_t ko = (size_t)kb * 32 * D_MODEL;
    const size_t vo = (size_t)kb * 32;
    // V: global->reg (issued first; ds_write waits vmcnt leaving K DMA in flight)
    f16x8 vh0 = ld8h(gvh + vo);
    f16x8 vh1 = ld8h(gvh + vo + (size_t)16 * T_SEQ);
    f16x8 vl0 = ld8h(gvl + vo);
    f16x8 vl1 = ld8h(gvl + vo + (size_t)16 * T_SEQ);
    // K: DMA
    gload16(gkh0 + ko, dkh0);  gload16(gkh1 + ko, dkh1);
    gload16(gkl0 + ko, dkl0);  gload16(gkl1 + ko, dkl1);
    // V: reg->LDS padded
    *(f16x8*)&Vth[vrow][vcol]      = vh0;
    *(f16x8*)&Vth[vrow + 16][vcol] = vh1;
    *(f16x8*)&Vtl[vrow][vcol]      = vl0;
    *(f16x8*)&Vtl[vrow + 16][vcol] = vl1;
    __syncthreads();

    f32x4 s0 = zero4(), s0x = zero4(), s1 = zero4(), s1x = zero4();
    #pragma unroll
    for (int c = 0; c < 4; ++c) {
      const int pk = ((4*c + lg) ^ (l16 & 7)) * 8;
      f16x8 kh0 = ld8h(&Ksh[l16][pk]);
      f16x8 kl0 = ld8h(&Ksl[l16][pk]);
      f16x8 kh1 = ld8h(&Ksh[16 + l16][pk]);
      f16x8 kl1 = ld8h(&Ksl[16 + l16][pk]);
      s0  = mfma16h(qf_h[c], kh0, s0);
      s0x = mfma16h(qf_h[c], kl0, s0x);
      s0x = mfma16h(qf_l[c], kh0, s0x);
      s1  = mfma16h(qf_h[c], kh1, s1);
      s1x = mfma16h(qf_h[c], kl1, s1x);
      s1x = mfma16h(qf_l[c], kh1, s1x);
    }

    float p0[4], p1[4], corrv[4];
    #pragma unroll
    for (int t = 0; t < 4; ++t) {
      int qrow = qb*64 + w*16 + lg*4 + t;
      float a  = (s0[t] + s0x[t] * RLOI) * scale;
      float bb = (s1[t] + s1x[t] * RLOI) * scale;
      if (kb*32      + l16 > qrow) a  = -1e9f;
      if (kb*32 + 16 + l16 > qrow) bb = -1e9f;
      float mx = fmaxf(a, bb);
      #pragma unroll
      for (int d = 1; d < 16; d <<= 1) mx = fmaxf(mx, __shfl_xor(mx, d, 64));
      float mnew = fmaxf(mrow[t], mx);
      float corr = __expf(mrow[t] - mnew);
      float e0 = __expf(a - mnew), e1 = __expf(bb - mnew);
      float ps = e0 + e1;
      #pragma unroll
      for (int d = 1; d < 16; d <<= 1) ps += __shfl_xor(ps, d, 64);
      drow[t] = drow[t] * corr + ps;
      mrow[t] = mnew;
      corrv[t] = corr;
      p0[t] = e0; p1[t] = e1;
    }
    #pragma unroll
    for (int df = 0; df < 8; ++df)
      #pragma unroll
      for (int t = 0; t < 4; ++t) { acc1[df][t] *= corrv[t]; acc2[df][t] *= corrv[t]; }

    // P (D-layout) -> per-wave LDS -> reload in A-frag layout (split pair).
    #pragma unroll
    for (int t = 0; t < 4; ++t) {
      _Float16 hh, ll;
      split1(p0[t], hh, ll);
      Psh[w][lg*4 + t][l16] = hh;  Psl[w][lg*4 + t][l16] = ll;
      split1(p1[t], hh, ll);
      Psh[w][lg*4 + t][16 + l16] = hh;  Psl[w][lg*4 + t][16 + l16] = ll;
    }
    asm volatile("s_waitcnt lgkmcnt(0)" ::: "memory");
    __builtin_amdgcn_sched_barrier(0);
    f16x8 pf_h = ld8h(&Psh[w][l16][lg*8]);
    f16x8 pf_l = ld8h(&Psl[w][l16][lg*8]);
    #pragma unroll
    for (int df = 0; df < 8; ++df) {
      f16x8 vh = ld8h(&Vth[df*16 + l16][lg*8]);
      f16x8 vl = ld8h(&Vtl[df*16 + l16][lg*8]);
      acc1[df] = mfma16h(pf_h, vh, acc1[df]);
      acc2[df] = mfma16h(pf_h, vl, acc2[df]);
      acc2[df] = mfma16h(pf_l, vh, acc2[df]);
    }
  }
  #pragma unroll
  for (int df = 0; df < 8; ++df)
    #pragma unroll
    for (int t = 0; t < 4; ++t) {
      float o = (acc1[df][t] + acc2[df][t] * RLOI) / drow[t];
      _Float16 hh, ll; split1(o, hh, ll);
      const size_t oo = hbase + (qrow0 + w*16 + lg*4 + t) * D_MODEL + df*16 + l16;
      Oh[oo] = hh; Ol[oo] = ll;
    }
}

// ---- prev pair: t==0 ? 0 : split(x_post[b,t-1,:]) ----
__global__ __launch_bounds__(256) void shiftprev_kernel(const float* __restrict__ xpost,
                                                        _Float16* __restrict__ ph,
                                                        _Float16* __restrict__ pl) {
  const int row = blockIdx.x;
  const int tpos = row & (T_SEQ - 1);
  const size_t o = (size_t)row * D_MODEL + threadIdx.x * 8;
  f16x8 hh, ll;
  if (tpos == 0) {
    #pragma unroll
    for (int i = 0; i < 8; ++i) { hh[i] = (_Float16)0.f; ll[i] = (_Float16)0.f; }
  } else {
    const float* src = xpost + o - D_MODEL;
    #pragma unroll
    for (int i = 0; i < 8; ++i) {
      _Float16 h, l; split1(src[i], h, l); hh[i] = h; ll[i] = l;
    }
  }
  *(f16x8*)(ph + o) = hh;
  *(f16x8*)(pl + o) = ll;
}

// ---- per-row err = mean_D (pred - (xpost - xorig))^2 ----
__global__ __launch_bounds__(256) void err_kernel(const float* __restrict__ pred,
                                                  const float* __restrict__ xpost,
                                                  const float* __restrict__ xorig,
                                                  float* __restrict__ err) {
  const int row = blockIdx.x, tid = threadIdx.x;
  const size_t base = (size_t)row * D_MODEL + tid * 8;
  const float* pp = pred + base;
  const float* ap = xpost + base;
  const float* op = xorig + base;
  float ss = 0.f;
  #pragma unroll
  for (int i = 0; i < 8; ++i) {
    float d = pp[i] - (ap[i] - op[i]);
    ss += d * d;
  }
  ss = wredsum(ss);
  __shared__ float red[4];
  if ((tid & 63) == 0) red[tid >> 6] = ss;
  __syncthreads();
  if (tid == 0) err[row] = (red[0]+red[1]+red[2]+red[3]) / (float)D_MODEL;
}

// ---- stats: mean/std of err -> tpn_loss, g_continuous, binary_targets ----
__global__ __launch_bounds__(1024) void stats_kernel(const float* __restrict__ err,
                                                     float* __restrict__ dout) {
  __shared__ float red[16];
  __shared__ float sh[2];
  const int tid = threadIdx.x;
  float s = 0.f;
  for (int i = tid; i < NTOK; i += 1024) s += err[i];
  s = wredsum(s);
  if ((tid & 63) == 0) red[tid >> 6] = s;
  __syncthreads();
  if (tid == 0) {
    float t = 0.f;
    for (int i = 0; i < 16; ++i) t += red[i];
    sh[0] = t / (float)NTOK;
  }
  __syncthreads();
  const float mean = sh[0];
  float v = 0.f;
  for (int i = tid; i < NTOK; i += 1024) { float d = err[i] - mean; v += d * d; }
  v = wredsum(v);
  __syncthreads();
  if ((tid & 63) == 0) red[tid >> 6] = v;
  __syncthreads();
  if (tid == 0) {
    float t = 0.f;
    for (int i = 0; i < 16; ++i) t += red[i];
    sh[1] = sqrtf(t / (float)NTOK);
    dout[OFF_TPN] = mean;   // tpn_loss == mean(err)
  }
  __syncthreads();
  const float stdv = sh[1];
  for (int i = tid; i < NTOK; i += 1024) {
    float z = (err[i] - mean) / (stdv + 1e-6f);
    dout[OFF_G + i] = 1.f / (1.f + expf(-z));
    dout[OFF_B + i] = (err[i] > mean) ? 1.f : 0.f;
  }
}

// ---- causal router scores/probs ----
__global__ __launch_bounds__(256) void cscore_kernel(const float* __restrict__ x,
                                                     const float* __restrict__ rwv,
                                                     const float* __restrict__ rbv,
                                                     float* __restrict__ cs,
                                                     float* __restrict__ probs) {
  const int row = blockIdx.x, tid = threadIdx.x;
  const float* xr = x + (size_t)row * D_MODEL + tid * 8;
  const float* wr = rwv + tid * 8;
  float s = 0.f;
  #pragma unroll
  for (int i = 0; i < 8; ++i) s += xr[i] * wr[i];
  s = wredsum(s);
  __shared__ float red[4];
  if ((tid & 63) == 0) red[tid >> 6] = s;
  __syncthreads();
  if (tid == 0) {
    float v = red[0]+red[1]+red[2]+red[3] + rbv[0];
    cs[row] = v;
    probs[row] = 1.f / (1.f + expf(-v));
  }
}

// ---- BCE-with-logits ----
__global__ __launch_bounds__(1024) void closs_kernel(const float* __restrict__ cs,
                                                     const float* __restrict__ tgt,
                                                     float* __restrict__ outv) {
  __shared__ float red[16];
  const int tid = threadIdx.x;
  float a = 0.f;
  for (int i = tid; i < NTOK; i += 1024) {
    float s = cs[i], t = tgt[i];
    a += fmaxf(s, 0.f) - s * t + log1pf(expf(-fabsf(s)));
  }
  a = wredsum(a);
  if ((tid & 63) == 0) red[tid >> 6] = a;
  __syncthreads();
  if (tid == 0) {
    float t = 0.f;
    for (int i = 0; i < 16; ++i) t += red[i];
    outv[0] = t / (float)NTOK;
  }
}

extern "C" void kernel_launch(void* const* d_in, const int* in_sizes, int n_in,
                              void* d_out, int out_size, void* d_ws, size_t ws_size,
                              hipStream_t stream) {
  (void)in_sizes; (void)n_in; (void)out_size; (void)ws_size;
  const float* x_in = (const float*)d_in[0];
  const float* q_w  = (const float*)d_in[1];
  const float* q_b  = (const float*)d_in[2];
  const float* k_w  = (const float*)d_in[3];
  const float* k_b  = (const float*)d_in[4];
  const float* v_w  = (const float*)d_in[5];
  const float* v_b  = (const float*)d_in[6];
  const float* o_w  = (const float*)d_in[7];
  const float* ln1  = (const float*)d_in[8];
  const float* ln2  = (const float*)d_in[9];
  const float* gw   = (const float*)d_in[10];
  const float* uw   = (const float*)d_in[11];
  const float* dw   = (const float*)d_in[12];
  const float* t1w  = (const float*)d_in[13];
  const float* t1b  = (const float*)d_in[14];
  const float* t2w  = (const float*)d_in[15];
  const float* t2b  = (const float*)d_in[16];
  const float* rw   = (const float*)d_in[17];
  const float* rb   = (const float*)d_in[18];
  float* out = (float*)d_out;
  char* ws = (char*)d_ws;

  // -------- workspace plan, peak 208 MiB (proven-safe envelope) --------
  _Float16* WQKVh = (_Float16*)(ws + 0);           // 3x [2048][2048]
  _Float16* WQKVl = (_Float16*)(ws + 25165824);
  _Float16* WOh   = (_Float16*)(ws + 0);
  _Float16* WOl   = (_Float16*)(ws + 8388608);
  _Float16* WDh   = (_Float16*)(ws + 0);           // [2048][4096] half
  _Float16* WDl   = (_Float16*)(ws + 16777216);
  _Float16* WT1h  = (_Float16*)(ws + 0);
  _Float16* WT1l  = (_Float16*)(ws + 8388608);
  _Float16* WT2h  = (_Float16*)(ws + 16777216);
  _Float16* WT2l  = (_Float16*)(ws + 25165824);
  _Float16* Hh    = (_Float16*)(ws + 50331648);
  _Float16* Hl    = (_Float16*)(ws + 67108864);
  _Float16* PREVh = Hh;
  _Float16* PREVl = Hl;
  _Float16* QKVh  = (_Float16*)(ws + 83886080);    // [3][4096][2048]; V part is VT
  _Float16* QKVl  = (_Float16*)(ws + 134217728);
  _Float16* CTXh  = (_Float16*)(ws + 184549376);
  _Float16* CTXl  = (_Float16*)(ws + 201326592);   // ends 218103808 (208 MiB)
  _Float16* WGh   = (_Float16*)(ws + 83886080);    // [4096][2048] half
  _Float16* WGl   = (_Float16*)(ws + 100663296);
  _Float16* WUh   = (_Float16*)(ws + 117440512);
  _Float16* WUl   = (_Float16*)(ws + 134217728);
  _Float16* MLPh  = (_Float16*)(ws + 150994944);   // [4096][4096] half
  _Float16* MLPl  = (_Float16*)(ws + 184549376);   // ends 218103808
  _Float16* A1h   = (_Float16*)(ws + 83886080);
  _Float16* A1l   = (_Float16*)(ws + 100663296);
  float*    PREDf = (float*)   (ws + 117440512);   // 32 MiB, ends 150994944
  float*    ERRf  = (float*)   (ws + 150994944);
  float*    CSf   = (float*)   (ws + 151011328);

  const size_t DD = (size_t)D_MODEL * D_MODEL;
  const size_t TD = (size_t)NTOK * D_MODEL;
  dim3 tb(32, 8);
  const dim3 gW22(64, 64);     // [2048]x[2048] split
  const dim3 gWg(128, 64);     // gw/uw half: C=4096, R=2048
  const dim3 gWd(64, 128);     // dw half:    C=2048, R=4096

  // 1) QKV weights -> A
  wsplit_kernel<<<gW22, tb, 0, stream>>>(q_w, WQKVh,        WQKVl,        D_MODEL, 0, 0, D_MODEL);
  wsplit_kernel<<<gW22, tb, 0, stream>>>(k_w, WQKVh + DD,   WQKVl + DD,   D_MODEL, 0, 0, D_MODEL);
  wsplit_kernel<<<gW22, tb, 0, stream>>>(v_w, WQKVh + 2*DD, WQKVl + 2*DD, D_MODEL, 0, 0, D_MODEL);
  // 2) h = rmsnorm(x, ln1) -> B
  rmsnorm_kernel<<<NTOK, 256, 0, stream>>>(x_in, ln1, Hh, Hl);
  // 3) fused QKV GEMM -> C (z selects Q/K/V; V written transposed [b*h][d][T])
  gemm2_kernel<1,true,true><<<dim3(16,32,3),256,0,stream>>>(
      Hh, Hl, WQKVh, WQKVl, q_b, k_b, v_b, nullptr, nullptr, nullptr,
      QKVh, QKVl, NTOK, D_MODEL, D_MODEL);
  // 4) RoPE in place on Q,K
  rope_kernel<<<NTOK, 256, 0, stream>>>(QKVh, QKVl, QKVh + TD, QKVl + TD);
  // 5) attention -> D (CTX)
  attn_kernel<<<dim3(T_SEQ/64, B_SZ*NHEAD), 256, 0, stream>>>(
      QKVh, QKVl, QKVh + TD, QKVl + TD, QKVh + 2*TD, QKVl + 2*TD, CTXh, CTXl);
  // 6) o_w -> A; x = x_in + ctx @ o_w -> out
  wsplit_kernel<<<gW22, tb, 0, stream>>>(o_w, WOh, WOl, D_MODEL, 0, 0, D_MODEL);
  gemm2_kernel<3,false,false><<<dim3(16,32),256,0,stream>>>(
      CTXh, CTXl, WOh, WOl, nullptr, nullptr, nullptr, x_in, nullptr, nullptr,
      out, nullptr, NTOK, D_MODEL, D_MODEL);
  // 7) h2 = rmsnorm(x, ln2) -> B
  rmsnorm_kernel<<<NTOK, 256, 0, stream>>>(out, ln2, Hh, Hl);
  // 8) FFN in two halves of F; down accumulates into out (split-K, fp32)
  for (int half = 0; half < 2; ++half) {
    const int f0 = half * (FFN/2);
    wsplit_kernel<<<gWg, tb, 0, stream>>>(gw, WGh, WGl, FFN, 0, f0, D_MODEL);
    wsplit_kernel<<<gWg, tb, 0, stream>>>(uw, WUh, WUl, FFN, 0, f0, D_MODEL);
    gemm2_kernel<0,true,false><<<dim3(32,32),256,0,stream>>>(
        Hh, Hl, WGh, WGl, nullptr, nullptr, nullptr, nullptr, nullptr, nullptr,
        MLPh, MLPl, NTOK, FFN/2, D_MODEL);
    gemm2_kernel<4,true,false><<<dim3(32,32),256,0,stream>>>(
        Hh, Hl, WUh, WUl, nullptr, nullptr, nullptr, nullptr, MLPh, MLPl,
        MLPh, MLPl, NTOK, FFN/2, D_MODEL);
    wsplit_kernel<<<gWd, tb, 0, stream>>>(dw, WDh, WDl, D_MODEL, f0, 0, FFN/2);
    gemm2_kernel<3,false,false><<<dim3(16,32),256,0,stream>>>(
        MLPh, MLPl, WDh, WDl, nullptr, nullptr, nullptr, out, nullptr, nullptr,
        out, nullptr, NTOK, D_MODEL, FFN/2);
  }
  // 9) TPN
  shiftprev_kernel<<<NTOK, 256, 0, stream>>>(out, PREVh, PREVl);
  wsplit_kernel<<<gW22, tb, 0, stream>>>(t1w, WT1h, WT1l, D_MODEL, 0, 0, D_MODEL);
  wsplit_kernel<<<gW22, tb, 0, stream>>>(t2w, WT2h, WT2l, D_MODEL, 0, 0, D_MODEL);
  gemm2_kernel<2,true,false><<<dim3(16,32),256,0,stream>>>(
      PREVh, PREVl, WT1h, WT1l, t1b, nullptr, nullptr, nullptr, nullptr, nullptr,
      A1h, A1l, NTOK, D_MODEL, D_MODEL);
  gemm2_kernel<1,false,false><<<dim3(16,32),256,0,stream>>>(
      A1h, A1l, WT2h, WT2l, t2b, nullptr, nullptr, nullptr, nullptr, nullptr,
      PREDf, nullptr, NTOK, D_MODEL, D_MODEL);
  // 10) losses / routers
  err_kernel<<<NTOK, 256, 0, stream>>>(PREDf, out, x_in, ERRf);
  stats_kernel<<<1, 1024, 0, stream>>>(ERRf, out);
  cscore_kernel<<<NTOK, 256, 0, stream>>>(x_in, rw, rb, CSf, out + OFF_CP);
  closs_kernel<<<1, 1024, 0, stream>>>(CSf, out + OFF_B, out + OFF_CL);
}

// Round 10
// 3132.844 us; speedup vs baseline: 1.0102x; 1.0102x over previous
//
#include <hip/hip_runtime.h>
#include <math.h>

#define B_SZ 2
#define T_SEQ 2048
#define D_MODEL 2048
#define NHEAD 16
#define HDIM 128
#define FFN 8192
#define NTOK (B_SZ*T_SEQ)   // 4096

// d_out layout (fp32): x_posterior | tpn_loss | causal_loss | g | binary | probs
#define OFF_TPN 8388608
#define OFF_CL  8388609
#define OFF_G   8388610
#define OFF_B   8392706
#define OFF_CP  8396802

#define RLO 1024.0f
#define RLOI 9.765625e-4f   // 1/1024

typedef __attribute__((ext_vector_type(8))) _Float16 f16x8;
typedef __attribute__((ext_vector_type(4))) float f32x4;
typedef unsigned int u32;
typedef const u32 __attribute__((address_space(1)))* gas_p;
typedef u32 __attribute__((address_space(3)))* las_p;

__device__ __forceinline__ void gload16(const _Float16* g, _Float16* l) {
  __builtin_amdgcn_global_load_lds((gas_p)g, (las_p)l, 16, 0, 0);
}
__device__ __forceinline__ f16x8 ld8h(const _Float16* p) {
  return *reinterpret_cast<const f16x8*>(p);
}
__device__ __forceinline__ f32x4 mfma16h(f16x8 a, f16x8 b, f32x4 c) {
  return __builtin_amdgcn_mfma_f32_16x16x32_f16(a, b, c, 0, 0, 0);
}
__device__ __forceinline__ f32x4 zero4() { f32x4 z = {0.f,0.f,0.f,0.f}; return z; }
__device__ __forceinline__ float wredsum(float v) {
  #pragma unroll
  for (int d = 1; d < 64; d <<= 1) v += __shfl_xor(v, d, 64);
  return v;
}
__device__ __forceinline__ void split1(float v, _Float16& h, _Float16& l) {
  _Float16 hh = (_Float16)v;
  h = hh;
  l = (_Float16)((v - (float)hh) * RLO);
}

// ---- weight sub-panel transpose + fp16 split ----
// dst[c][r] (c<C, r<R, dst row stride R) = split(src[(r0+r)*srcStride + c0+c])
__global__ __launch_bounds__(256) void wsplit_kernel(const float* __restrict__ src,
                                                     _Float16* __restrict__ dhi,
                                                     _Float16* __restrict__ dlo,
                                                     int srcStride, int r0, int c0,
                                                     int R) {
  __shared__ float tile[32][33];
  int cb = blockIdx.x * 32, rb = blockIdx.y * 32;
  int tx = threadIdx.x, ty = threadIdx.y;
  #pragma unroll
  for (int i = 0; i < 4; ++i)
    tile[ty + i*8][tx] = src[(size_t)(r0 + rb + ty + i*8) * srcStride + c0 + cb + tx];
  __syncthreads();
  #pragma unroll
  for (int i = 0; i < 4; ++i) {
    float v = tile[tx][ty + i*8];
    _Float16 h, l; split1(v, h, l);
    size_t idx = (size_t)(cb + ty + i*8) * R + rb + tx;
    dhi[idx] = h; dlo[idx] = l;
  }
}

// ---- RMSNorm: fp32 in -> f16 pair out ----
__global__ __launch_bounds__(256) void rmsnorm_kernel(const float* __restrict__ x,
                                                      const float* __restrict__ wgt,
                                                      _Float16* __restrict__ oh,
                                                      _Float16* __restrict__ ol) {
  const int row = blockIdx.x, tid = threadIdx.x;
  const float* xr = x + (size_t)row * D_MODEL;
  float4 v0 = *(const float4*)(xr + tid*8);
  float4 v1 = *(const float4*)(xr + tid*8 + 4);
  float ss = v0.x*v0.x + v0.y*v0.y + v0.z*v0.z + v0.w*v0.w
           + v1.x*v1.x + v1.y*v1.y + v1.z*v1.z + v1.w*v1.w;
  ss = wredsum(ss);
  __shared__ float red[4];
  if ((tid & 63) == 0) red[tid >> 6] = ss;
  __syncthreads();
  float tot = red[0] + red[1] + red[2] + red[3];
  float inv = 1.f / sqrtf(tot / (float)D_MODEL + 1e-6f);
  float4 w0 = *(const float4*)(wgt + tid*8);
  float4 w1 = *(const float4*)(wgt + tid*8 + 4);
  float f[8];
  f[0]=v0.x*inv*w0.x; f[1]=v0.y*inv*w0.y; f[2]=v0.z*inv*w0.z; f[3]=v0.w*inv*w0.w;
  f[4]=v1.x*inv*w1.x; f[5]=v1.y*inv*w1.y; f[6]=v1.z*inv*w1.z; f[7]=v1.w*inv*w1.w;
  f16x8 hh, ll;
  #pragma unroll
  for (int i = 0; i < 8; ++i) { _Float16 h, l; split1(f[i], h, l); hh[i]=h; ll[i]=l; }
  *(f16x8*)(oh + (size_t)row * D_MODEL + tid*8) = hh;
  *(f16x8*)(ol + (size_t)row * D_MODEL + tid*8) = ll;
}

// ---- all-pair GEMM: C[M][N] = (Ah+Al/1024)[M][K] @ (Bh+Bl/1024)[N][K]^T ----
// 128x128 tile, BK=32, 4 waves 2x2, 3x mfma_f32_16x16x32_f16 per frag pair.
// Double-buffered LDS (64 KiB) + cross-step prefetch (T3-minimum).
// Tile order: grouped (GROUP_M=8) then XCD-chunked -> supertile L2 reuse.
// Staging: global_load_lds width-16, 16B chunks XOR-swizzled on BOTH sides.
// MODE: 0 plain, 1 +bias, 2 silu(v+bias), 3 +resid, 4 silu(g)*v (g pair)
// QKV: blockIdx.z selects Q/K/V; V is written TRANSPOSED to [b*h][d][T].
template<int MODE, bool OUT_SPLIT, bool QKV>
__global__ __launch_bounds__(256) void gemm2_kernel(
    const _Float16* __restrict__ Ahi, const _Float16* __restrict__ Alo,
    const _Float16* __restrict__ Bhi, const _Float16* __restrict__ Blo,
    const float* __restrict__ b0, const float* __restrict__ b1,
    const float* __restrict__ b2, const float* __restrict__ resid,
    const _Float16* __restrict__ ghi, const _Float16* __restrict__ glo,
    void* __restrict__ C1, void* __restrict__ C2,
    int M, int N, int K) {
  // grouped + XCD-chunked tile order (nbm always a multiple of 8 here)
  const int nbn = gridDim.x, nbm = gridDim.y;
  int bid = blockIdx.y * nbn + blockIdx.x;
  bid = (bid & 7) * ((nbn * nbm) >> 3) + (bid >> 3);   // XCD chunking
  const int nig = nbn << 3;
  const int gid = bid / nig, rem = bid - gid * nig;
  const int by = (gid << 3) + (rem & 7);
  const int bx = rem >> 3;
  int sel = 0;
  const float* bias = b0;
  size_t cbase = 0, bwoff = 0;
  if (QKV) {
    sel = blockIdx.z;
    bias = (sel == 0) ? b0 : ((sel == 1) ? b1 : b2);
    bwoff = (size_t)sel * D_MODEL * D_MODEL;
    cbase = (size_t)sel * (size_t)NTOK * D_MODEL;
  }
  const int n0 = bx * 128, m0 = by * 128;
  const int tid = threadIdx.x, lane = tid & 63, wv = tid >> 6;
  const int wr = wv >> 1, wc = wv & 1;
  const int l16 = lane & 15, lg = lane >> 4;
  // [buf][arr][128][32] halves; arr: 0=Ah 1=Al 2=Bh 3=Bl
  __shared__ _Float16 SH[2 * 4 * 128 * 32];
  f32x4 acc1[4][4], acc2[4][4];
  #pragma unroll
  for (int i = 0; i < 4; ++i)
    #pragma unroll
    for (int j = 0; j < 4; ++j) { acc1[i][j] = zero4(); acc2[i][j] = zero4(); }
  // staging: wave wv covers rows [wv*32, wv*32+32); 2 issues of 16 rows/array.
  const int srow = wv * 32 + (lane >> 2);
  const int scol = ((lane & 3) ^ ((lane >> 2) & 3)) * 8;
  const _Float16* ga0  = Ahi + (size_t)(m0 + srow) * K + scol;
  const _Float16* ga1  = ga0 + (size_t)16 * K;
  const _Float16* gal0 = Alo + (size_t)(m0 + srow) * K + scol;
  const _Float16* gal1 = gal0 + (size_t)16 * K;
  const _Float16* gb0  = Bhi + bwoff + (size_t)(n0 + srow) * K + scol;
  const _Float16* gb1  = gb0 + (size_t)16 * K;
  const _Float16* gbl0 = Blo + bwoff + (size_t)(n0 + srow) * K + scol;
  const _Float16* gbl1 = gbl0 + (size_t)16 * K;
  const int dbase = wv * 32 * 32;          // element offset within array
  const int csw = (lg ^ (l16 & 3)) * 8;    // swizzled read chunk offset

  #define STAGE(buf, kk) do {                                   \
    _Float16* sb = SH + (buf) * 16384;                          \
    gload16(ga0  + (kk), sb          + dbase);                  \
    gload16(ga1  + (kk), sb          + dbase + 512);            \
    gload16(gal0 + (kk), sb + 4096  + dbase);                   \
    gload16(gal1 + (kk), sb + 4096  + dbase + 512);             \
    gload16(gb0  + (kk), sb + 8192  + dbase);                   \
    gload16(gb1  + (kk), sb + 8192  + dbase + 512);             \
    gload16(gbl0 + (kk), sb + 12288 + dbase);                   \
    gload16(gbl1 + (kk), sb + 12288 + dbase + 512);             \
  } while (0)

  int cur = 0;
  STAGE(0, 0);
  __syncthreads();
  for (int kk = 0; kk < K; kk += 32) {
    if (kk + 32 < K) STAGE(cur ^ 1, kk + 32);   // prefetch next step
    const _Float16* sb = SH + cur * 16384;
    f16x8 af_h[4], af_l[4];
    #pragma unroll
    for (int i = 0; i < 4; ++i) {
      const int off = (wr*64 + i*16 + l16) * 32 + csw;
      af_h[i] = ld8h(sb + off);
      af_l[i] = ld8h(sb + 4096 + off);
    }
    #pragma unroll
    for (int j = 0; j < 4; ++j) {
      const int offb = (wc*64 + j*16 + l16) * 32 + csw;
      f16x8 bh = ld8h(sb + 8192 + offb);
      f16x8 bl = ld8h(sb + 12288 + offb);
      #pragma unroll
      for (int i = 0; i < 4; ++i) {
        acc1[i][j] = mfma16h(af_h[i], bh, acc1[i][j]);
        acc2[i][j] = mfma16h(af_h[i], bl, acc2[i][j]);
        acc2[i][j] = mfma16h(af_l[i], bh, acc2[i][j]);
      }
    }
    __syncthreads();   // drains prefetch vmcnt + publishes buf^1
    cur ^= 1;
  }
  #undef STAGE
  #pragma unroll
  for (int i = 0; i < 4; ++i) {
    const int row0 = m0 + wr*64 + i*16 + lg*4;   // D: row=(lane>>4)*4+t, col=lane&15
    #pragma unroll
    for (int j = 0; j < 4; ++j) {
      const int col = n0 + wc*64 + j*16 + l16;
      float bv = (MODE == 1 || MODE == 2) ? bias[col] : 0.f;
      #pragma unroll
      for (int t = 0; t < 4; ++t) {
        const int row = row0 + t;
        size_t idx;
        if (QKV && sel == 2)   // V -> transposed [b*h][d][T] layout
          idx = cbase + (size_t)(row >> 11) * ((size_t)D_MODEL * T_SEQ)
                      + (size_t)col * T_SEQ + (row & (T_SEQ - 1));
        else
          idx = cbase + (size_t)row * N + col;
        float v = acc1[i][j][t] + acc2[i][j][t] * RLOI + bv;
        if (MODE == 2) v = v / (1.f + __expf(-v));
        if (MODE == 3) v += resid[idx];
        if (MODE == 4) {
          float g = (float)ghi[idx] + (float)glo[idx] * RLOI;
          v = g / (1.f + __expf(-g)) * v;
        }
        if (OUT_SPLIT) {
          _Float16 h, l; split1(v, h, l);
          ((_Float16*)C1)[idx] = h;
          ((_Float16*)C2)[idx] = l;
        } else {
          ((float*)C1)[idx] = v;
        }
      }
    }
  }
}

// ---- RoPE (neox), in place on f16 pairs; one token-row per block ----
__global__ __launch_bounds__(256) void rope_kernel(_Float16* __restrict__ Qh,
                                                   _Float16* __restrict__ Ql,
                                                   _Float16* __restrict__ Kh,
                                                   _Float16* __restrict__ Kl) {
  const int row = blockIdx.x;
  const int tpos = row & (T_SEQ - 1);
  __shared__ float svs[64], cvs[64];
  if (threadIdx.x < 64) {
    double invf = exp(-(double)threadIdx.x * (9.210340371976184 / 64.0));
    double ph = fmod((double)tpos * invf, 6.283185307179586476925);
    sincosf((float)ph, &svs[threadIdx.x], &cvs[threadIdx.x]);
  }
  __syncthreads();
  for (int item = threadIdx.x; item < NHEAD * 64; item += 256) {
    const int h = item >> 6, d = item & 63;
    const float sv = svs[d], cv = cvs[d];
    const size_t i0 = (size_t)row * D_MODEL + h*HDIM + d;
    const size_t i1 = i0 + 64;
    float q0 = (float)Qh[i0] + (float)Ql[i0]*RLOI;
    float q1 = (float)Qh[i1] + (float)Ql[i1]*RLOI;
    float k0 = (float)Kh[i0] + (float)Kl[i0]*RLOI;
    float k1 = (float)Kh[i1] + (float)Kl[i1]*RLOI;
    _Float16 hh, ll;
    split1(q0*cv - q1*sv, hh, ll); Qh[i0]=hh; Ql[i0]=ll;
    split1(q1*cv + q0*sv, hh, ll); Qh[i1]=hh; Ql[i1]=ll;
    split1(k0*cv - k1*sv, hh, ll); Kh[i0]=hh; Kl[i0]=ll;
    split1(k1*cv + k0*sv, hh, ll); Kh[i1]=hh; Kl[i1]=ll;
  }
}

// ---- flash attention on pairs: 64 q-rows/block, KV tiles of 32 ----
// R7-proven structure: K staged via global_load_lds into [32][128] with
// chunk^(row&7) XOR swizzle (source + ds_read side); V pre-transposed in
// global ([b*h][d][T]) and DMA-staged linearly into [128][32]. 42KB LDS,
// 124 VGPR, 3 blocks/CU. Only delta vs R7: expf -> __expf (validated).
__global__ __launch_bounds__(256) void attn_kernel(
    const _Float16* __restrict__ Qh, const _Float16* __restrict__ Ql,
    const _Float16* __restrict__ Kh, const _Float16* __restrict__ Kl,
    const _Float16* __restrict__ VTh, const _Float16* __restrict__ VTl,
    _Float16* __restrict__ Oh, _Float16* __restrict__ Ol) {
  const int qb = (int)gridDim.x - 1 - (int)blockIdx.x;  // heavy blocks first
  const int bhid = blockIdx.y;
  const int b = bhid >> 4, h = bhid & 15;
  const int tid = threadIdx.x, lane = tid & 63, w = tid >> 6;
  const int l16 = lane & 15, lg = lane >> 4;
  __shared__ _Float16 Ksh[32][128], Ksl[32][128];
  __shared__ _Float16 Vth[128][32], Vtl[128][32];
  __shared__ _Float16 Psh[4][16][40], Psl[4][16][40];
  const size_t hbase  = (size_t)b * T_SEQ * D_MODEL + (size_t)h * HDIM;
  const size_t vtbase = (size_t)bhid * (size_t)HDIM * T_SEQ;
  const size_t qrow0 = (size_t)qb * 64;

  f16x8 qf_h[4], qf_l[4];
  {
    const size_t qoff = hbase + (qrow0 + w*16 + l16) * D_MODEL + lg*8;
    #pragma unroll
    for (int c = 0; c < 4; ++c) {
      qf_h[c] = ld8h(Qh + qoff + c*32);
      qf_l[c] = ld8h(Ql + qoff + c*32);
    }
  }
  f32x4 acc1[8], acc2[8];
  #pragma unroll
  for (int df = 0; df < 8; ++df) { acc1[df] = zero4(); acc2[df] = zero4(); }
  float mrow[4] = {-3e38f,-3e38f,-3e38f,-3e38f};
  float drow[4] = {0.f,0.f,0.f,0.f};

  // staging pointers (DMA; K source chunk-XOR-swizzled, V^T linear)
  const int krow = w*8 + (lane >> 4);
  const int kch0 = ((lane & 15) ^ (krow & 7)) * 8;
  const int kch1 = ((lane & 15) ^ ((krow + 4) & 7)) * 8;
  const _Float16* gkh0 = Kh + hbase + (size_t)krow * D_MODEL + kch0;
  const _Float16* gkh1 = Kh + hbase + (size_t)(krow + 4) * D_MODEL + kch1;
  const _Float16* gkl0 = Kl + hbase + (size_t)krow * D_MODEL + kch0;
  const _Float16* gkl1 = Kl + hbase + (size_t)(krow + 4) * D_MODEL + kch1;
  _Float16* dkh0 = &Ksh[w*8][0];   _Float16* dkh1 = &Ksh[w*8+4][0];
  _Float16* dkl0 = &Ksl[w*8][0];   _Float16* dkl1 = &Ksl[w*8+4][0];
  const int vrow = w*32 + (lane >> 2);
  const int vcol = (lane & 3) * 8;
  const _Float16* gvh0 = VTh + vtbase + (size_t)vrow * T_SEQ + vcol;
  const _Float16* gvh1 = gvh0 + (size_t)16 * T_SEQ;
  const _Float16* gvl0 = VTl + vtbase + (size_t)vrow * T_SEQ + vcol;
  const _Float16* gvl1 = gvl0 + (size_t)16 * T_SEQ;
  _Float16* dvh0 = &Vth[w*32][0];  _Float16* dvh1 = &Vth[w*32+16][0];
  _Float16* dvl0 = &Vtl[w*32][0];  _Float16* dvl1 = &Vtl[w*32+16][0];

  const int nkb = (qb + 1) * 2;
  const float scale = 0.088388347648318447f;  // 1/sqrt(128)

  for (int kb = 0; kb < nkb; ++kb) {
    __syncthreads();
    const size_t ko = (size_t)kb * 32 * D_MODEL;
    const size_t vo = (size_t)kb * 32;
    gload16(gkh0 + ko, dkh0);  gload16(gkh1 + ko, dkh1);
    gload16(gkl0 + ko, dkl0);  gload16(gkl1 + ko, dkl1);
    gload16(gvh0 + vo, dvh0);  gload16(gvh1 + vo, dvh1);
    gload16(gvl0 + vo, dvl0);  gload16(gvl1 + vo, dvl1);
    __syncthreads();

    f32x4 s0 = zero4(), s0x = zero4(), s1 = zero4(), s1x = zero4();
    #pragma unroll
    for (int c = 0; c < 4; ++c) {
      const int pk = ((4*c + lg) ^ (l16 & 7)) * 8;
      f16x8 kh0 = ld8h(&Ksh[l16][pk]);
      f16x8 kl0 = ld8h(&Ksl[l16][pk]);
      f16x8 kh1 = ld8h(&Ksh[16 + l16][pk]);
      f16x8 kl1 = ld8h(&Ksl[16 + l16][pk]);
      s0  = mfma16h(qf_h[c], kh0, s0);
      s0x = mfma16h(qf_h[c], kl0, s0x);
      s0x = mfma16h(qf_l[c], kh0, s0x);
      s1  = mfma16h(qf_h[c], kh1, s1);
      s1x = mfma16h(qf_h[c], kl1, s1x);
      s1x = mfma16h(qf_l[c], kh1, s1x);
    }

    float p0[4], p1[4], corrv[4];
    #pragma unroll
    for (int t = 0; t < 4; ++t) {
      int qrow = qb*64 + w*16 + lg*4 + t;
      float a  = (s0[t] + s0x[t] * RLOI) * scale;
      float bb = (s1[t] + s1x[t] * RLOI) * scale;
      if (kb*32      + l16 > qrow) a  = -1e9f;
      if (kb*32 + 16 + l16 > qrow) bb = -1e9f;
      float mx = fmaxf(a, bb);
      #pragma unroll
      for (int d = 1; d < 16; d <<= 1) mx = fmaxf(mx, __shfl_xor(mx, d, 64));
      float mnew = fmaxf(mrow[t], mx);
      float corr = __expf(mrow[t] - mnew);
      float e0 = __expf(a - mnew), e1 = __expf(bb - mnew);
      float ps = e0 + e1;
      #pragma unroll
      for (int d = 1; d < 16; d <<= 1) ps += __shfl_xor(ps, d, 64);
      drow[t] = drow[t] * corr + ps;
      mrow[t] = mnew;
      corrv[t] = corr;
      p0[t] = e0; p1[t] = e1;
    }
    #pragma unroll
    for (int df = 0; df < 8; ++df)
      #pragma unroll
      for (int t = 0; t < 4; ++t) { acc1[df][t] *= corrv[t]; acc2[df][t] *= corrv[t]; }

    // P (D-layout) -> per-wave LDS -> reload in A-frag layout (split pair).
    #pragma unroll
    for (int t = 0; t < 4; ++t) {
      _Float16 hh, ll;
      split1(p0[t], hh, ll);
      Psh[w][lg*4 + t][l16] = hh;  Psl[w][lg*4 + t][l16] = ll;
      split1(p1[t], hh, ll);
      Psh[w][lg*4 + t][16 + l16] = hh;  Psl[w][lg*4 + t][16 + l16] = ll;
    }
    asm volatile("s_waitcnt lgkmcnt(0)" ::: "memory");
    __builtin_amdgcn_sched_barrier(0);
    f16x8 pf_h = ld8h(&Psh[w][l16][lg*8]);
    f16x8 pf_l = ld8h(&Psl[w][l16][lg*8]);
    #pragma unroll
    for (int df = 0; df < 8; ++df) {
      f16x8 vh = ld8h(&Vth[df*16 + l16][lg*8]);
      f16x8 vl = ld8h(&Vtl[df*16 + l16][lg*8]);
      acc1[df] = mfma16h(pf_h, vh, acc1[df]);
      acc2[df] = mfma16h(pf_h, vl, acc2[df]);
      acc2[df] = mfma16h(pf_l, vh, acc2[df]);
    }
  }
  #pragma unroll
  for (int df = 0; df < 8; ++df)
    #pragma unroll
    for (int t = 0; t < 4; ++t) {
      float o = (acc1[df][t] + acc2[df][t] * RLOI) / drow[t];
      _Float16 hh, ll; split1(o, hh, ll);
      const size_t oo = hbase + (qrow0 + w*16 + lg*4 + t) * D_MODEL + df*16 + l16;
      Oh[oo] = hh; Ol[oo] = ll;
    }
}

// ---- prev pair: t==0 ? 0 : split(x_post[b,t-1,:]) ----
__global__ __launch_bounds__(256) void shiftprev_kernel(const float* __restrict__ xpost,
                                                        _Float16* __restrict__ ph,
                                                        _Float16* __restrict__ pl) {
  const int row = blockIdx.x;
  const int tpos = row & (T_SEQ - 1);
  const size_t o = (size_t)row * D_MODEL + threadIdx.x * 8;
  f16x8 hh, ll;
  if (tpos == 0) {
    #pragma unroll
    for (int i = 0; i < 8; ++i) { hh[i] = (_Float16)0.f; ll[i] = (_Float16)0.f; }
  } else {
    const float* src = xpost + o - D_MODEL;
    #pragma unroll
    for (int i = 0; i < 8; ++i) {
      _Float16 h, l; split1(src[i], h, l); hh[i] = h; ll[i] = l;
    }
  }
  *(f16x8*)(ph + o) = hh;
  *(f16x8*)(pl + o) = ll;
}

// ---- per-row err = mean_D (pred - (xpost - xorig))^2 ----
__global__ __launch_bounds__(256) void err_kernel(const float* __restrict__ pred,
                                                  const float* __restrict__ xpost,
                                                  const float* __restrict__ xorig,
                                                  float* __restrict__ err) {
  const int row = blockIdx.x, tid = threadIdx.x;
  const size_t base = (size_t)row * D_MODEL + tid * 8;
  const float* pp = pred + base;
  const float* ap = xpost + base;
  const float* op = xorig + base;
  float ss = 0.f;
  #pragma unroll
  for (int i = 0; i < 8; ++i) {
    float d = pp[i] - (ap[i] - op[i]);
    ss += d * d;
  }
  ss = wredsum(ss);
  __shared__ float red[4];
  if ((tid & 63) == 0) red[tid >> 6] = ss;
  __syncthreads();
  if (tid == 0) err[row] = (red[0]+red[1]+red[2]+red[3]) / (float)D_MODEL;
}

// ---- stats: mean/std of err -> tpn_loss, g_continuous, binary_targets ----
__global__ __launch_bounds__(1024) void stats_kernel(const float* __restrict__ err,
                                                     float* __restrict__ dout) {
  __shared__ float red[16];
  __shared__ float sh[2];
  const int tid = threadIdx.x;
  float s = 0.f;
  for (int i = tid; i < NTOK; i += 1024) s += err[i];
  s = wredsum(s);
  if ((tid & 63) == 0) red[tid >> 6] = s;
  __syncthreads();
  if (tid == 0) {
    float t = 0.f;
    for (int i = 0; i < 16; ++i) t += red[i];
    sh[0] = t / (float)NTOK;
  }
  __syncthreads();
  const float mean = sh[0];
  float v = 0.f;
  for (int i = tid; i < NTOK; i += 1024) { float d = err[i] - mean; v += d * d; }
  v = wredsum(v);
  __syncthreads();
  if ((tid & 63) == 0) red[tid >> 6] = v;
  __syncthreads();
  if (tid == 0) {
    float t = 0.f;
    for (int i = 0; i < 16; ++i) t += red[i];
    sh[1] = sqrtf(t / (float)NTOK);
    dout[OFF_TPN] = mean;   // tpn_loss == mean(err)
  }
  __syncthreads();
  const float stdv = sh[1];
  for (int i = tid; i < NTOK; i += 1024) {
    float z = (err[i] - mean) / (stdv + 1e-6f);
    dout[OFF_G + i] = 1.f / (1.f + expf(-z));
    dout[OFF_B + i] = (err[i] > mean) ? 1.f : 0.f;
  }
}

// ---- causal router scores/probs ----
__global__ __launch_bounds__(256) void cscore_kernel(const float* __restrict__ x,
                                                     const float* __restrict__ rwv,
                                                     const float* __restrict__ rbv,
                                                     float* __restrict__ cs,
                                                     float* __restrict__ probs) {
  const int row = blockIdx.x, tid = threadIdx.x;
  const float* xr = x + (size_t)row * D_MODEL + tid * 8;
  const float* wr = rwv + tid * 8;
  float s = 0.f;
  #pragma unroll
  for (int i = 0; i < 8; ++i) s += xr[i] * wr[i];
  s = wredsum(s);
  __shared__ float red[4];
  if ((tid & 63) == 0) red[tid >> 6] = s;
  __syncthreads();
  if (tid == 0) {
    float v = red[0]+red[1]+red[2]+red[3] + rbv[0];
    cs[row] = v;
    probs[row] = 1.f / (1.f + expf(-v));
  }
}

// ---- BCE-with-logits ----
__global__ __launch_bounds__(1024) void closs_kernel(const float* __restrict__ cs,
                                                     const float* __restrict__ tgt,
                                                     float* __restrict__ outv) {
  __shared__ float red[16];
  const int tid = threadIdx.x;
  float a = 0.f;
  for (int i = tid; i < NTOK; i += 1024) {
    float s = cs[i], t = tgt[i];
    a += fmaxf(s, 0.f) - s * t + log1pf(expf(-fabsf(s)));
  }
  a = wredsum(a);
  if ((tid & 63) == 0) red[tid >> 6] = a;
  __syncthreads();
  if (tid == 0) {
    float t = 0.f;
    for (int i = 0; i < 16; ++i) t += red[i];
    outv[0] = t / (float)NTOK;
  }
}

extern "C" void kernel_launch(void* const* d_in, const int* in_sizes, int n_in,
                              void* d_out, int out_size, void* d_ws, size_t ws_size,
                              hipStream_t stream) {
  (void)in_sizes; (void)n_in; (void)out_size; (void)ws_size;
  const float* x_in = (const float*)d_in[0];
  const float* q_w  = (const float*)d_in[1];
  const float* q_b  = (const float*)d_in[2];
  const float* k_w  = (const float*)d_in[3];
  const float* k_b  = (const float*)d_in[4];
  const float* v_w  = (const float*)d_in[5];
  const float* v_b  = (const float*)d_in[6];
  const float* o_w  = (const float*)d_in[7];
  const float* ln1  = (const float*)d_in[8];
  const float* ln2  = (const float*)d_in[9];
  const float* gw   = (const float*)d_in[10];
  const float* uw   = (const float*)d_in[11];
  const float* dw   = (const float*)d_in[12];
  const float* t1w  = (const float*)d_in[13];
  const float* t1b  = (const float*)d_in[14];
  const float* t2w  = (const float*)d_in[15];
  const float* t2b  = (const float*)d_in[16];
  const float* rw   = (const float*)d_in[17];
  const float* rb   = (const float*)d_in[18];
  float* out = (float*)d_out;
  char* ws = (char*)d_ws;

  // -------- workspace plan, peak 208 MiB (proven-safe envelope) --------
  _Float16* WQKVh = (_Float16*)(ws + 0);           // 3x [2048][2048]
  _Float16* WQKVl = (_Float16*)(ws + 25165824);
  _Float16* WOh   = (_Float16*)(ws + 0);
  _Float16* WOl   = (_Float16*)(ws + 8388608);
  _Float16* WDh   = (_Float16*)(ws + 0);           // [2048][4096] half
  _Float16* WDl   = (_Float16*)(ws + 16777216);
  _Float16* WT1h  = (_Float16*)(ws + 0);
  _Float16* WT1l  = (_Float16*)(ws + 8388608);
  _Float16* WT2h  = (_Float16*)(ws + 16777216);
  _Float16* WT2l  = (_Float16*)(ws + 25165824);
  _Float16* Hh    = (_Float16*)(ws + 50331648);
  _Float16* Hl    = (_Float16*)(ws + 67108864);
  _Float16* PREVh = Hh;
  _Float16* PREVl = Hl;
  _Float16* QKVh  = (_Float16*)(ws + 83886080);    // [3][4096][2048]; V part is VT
  _Float16* QKVl  = (_Float16*)(ws + 134217728);
  _Float16* CTXh  = (_Float16*)(ws + 184549376);
  _Float16* CTXl  = (_Float16*)(ws + 201326592);   // ends 218103808 (208 MiB)
  _Float16* WGh   = (_Float16*)(ws + 83886080);    // [4096][2048] half
  _Float16* WGl   = (_Float16*)(ws + 100663296);
  _Float16* WUh   = (_Float16*)(ws + 117440512);
  _Float16* WUl   = (_Float16*)(ws + 134217728);
  _Float16* MLPh  = (_Float16*)(ws + 150994944);   // [4096][4096] half
  _Float16* MLPl  = (_Float16*)(ws + 184549376);   // ends 218103808
  _Float16* A1h   = (_Float16*)(ws + 83886080);
  _Float16* A1l   = (_Float16*)(ws + 100663296);
  float*    PREDf = (float*)   (ws + 117440512);   // 32 MiB, ends 150994944
  float*    ERRf  = (float*)   (ws + 150994944);
  float*    CSf   = (float*)   (ws + 151011328);

  const size_t DD = (size_t)D_MODEL * D_MODEL;
  const size_t TD = (size_t)NTOK * D_MODEL;
  dim3 tb(32, 8);
  const dim3 gW22(64, 64);     // [2048]x[2048] split
  const dim3 gWg(128, 64);     // gw/uw half: C=4096, R=2048
  const dim3 gWd(64, 128);     // dw half:    C=2048, R=4096

  // 1) QKV weights -> A
  wsplit_kernel<<<gW22, tb, 0, stream>>>(q_w, WQKVh,        WQKVl,        D_MODEL, 0, 0, D_MODEL);
  wsplit_kernel<<<gW22, tb, 0, stream>>>(k_w, WQKVh + DD,   WQKVl + DD,   D_MODEL, 0, 0, D_MODEL);
  wsplit_kernel<<<gW22, tb, 0, stream>>>(v_w, WQKVh + 2*DD, WQKVl + 2*DD, D_MODEL, 0, 0, D_MODEL);
  // 2) h = rmsnorm(x, ln1) -> B
  rmsnorm_kernel<<<NTOK, 256, 0, stream>>>(x_in, ln1, Hh, Hl);
  // 3) fused QKV GEMM -> C (z selects Q/K/V; V written transposed [b*h][d][T])
  gemm2_kernel<1,true,true><<<dim3(16,32,3),256,0,stream>>>(
      Hh, Hl, WQKVh, WQKVl, q_b, k_b, v_b, nullptr, nullptr, nullptr,
      QKVh, QKVl, NTOK, D_MODEL, D_MODEL);
  // 4) RoPE in place on Q,K
  rope_kernel<<<NTOK, 256, 0, stream>>>(QKVh, QKVl, QKVh + TD, QKVl + TD);
  // 5) attention -> D (CTX)
  attn_kernel<<<dim3(T_SEQ/64, B_SZ*NHEAD), 256, 0, stream>>>(
      QKVh, QKVl, QKVh + TD, QKVl + TD, QKVh + 2*TD, QKVl + 2*TD, CTXh, CTXl);
  // 6) o_w -> A; x = x_in + ctx @ o_w -> out
  wsplit_kernel<<<gW22, tb, 0, stream>>>(o_w, WOh, WOl, D_MODEL, 0, 0, D_MODEL);
  gemm2_kernel<3,false,false><<<dim3(16,32),256,0,stream>>>(
      CTXh, CTXl, WOh, WOl, nullptr, nullptr, nullptr, x_in, nullptr, nullptr,
      out, nullptr, NTOK, D_MODEL, D_MODEL);
  // 7) h2 = rmsnorm(x, ln2) -> B
  rmsnorm_kernel<<<NTOK, 256, 0, stream>>>(out, ln2, Hh, Hl);
  // 8) FFN in two halves of F; down accumulates into out (split-K, fp32)
  for (int half = 0; half < 2; ++half) {
    const int f0 = half * (FFN/2);
    wsplit_kernel<<<gWg, tb, 0, stream>>>(gw, WGh, WGl, FFN, 0, f0, D_MODEL);
    wsplit_kernel<<<gWg, tb, 0, stream>>>(uw, WUh, WUl, FFN, 0, f0, D_MODEL);
    gemm2_kernel<0,true,false><<<dim3(32,32),256,0,stream>>>(
        Hh, Hl, WGh, WGl, nullptr, nullptr, nullptr, nullptr, nullptr, nullptr,
        MLPh, MLPl, NTOK, FFN/2, D_MODEL);
    gemm2_kernel<4,true,false><<<dim3(32,32),256,0,stream>>>(
        Hh, Hl, WUh, WUl, nullptr, nullptr, nullptr, nullptr, MLPh, MLPl,
        MLPh, MLPl, NTOK, FFN/2, D_MODEL);
    wsplit_kernel<<<gWd, tb, 0, stream>>>(dw, WDh, WDl, D_MODEL, f0, 0, FFN/2);
    gemm2_kernel<3,false,false><<<dim3(16,32),256,0,stream>>>(
        MLPh, MLPl, WDh, WDl, nullptr, nullptr, nullptr, out, nullptr, nullptr,
        out, nullptr, NTOK, D_MODEL, FFN/2);
  }
  // 9) TPN
  shiftprev_kernel<<<NTOK, 256, 0, stream>>>(out, PREVh, PREVl);
  wsplit_kernel<<<gW22, tb, 0, stream>>>(t1w, WT1h, WT1l, D_MODEL, 0, 0, D_MODEL);
  wsplit_kernel<<<gW22, tb, 0, stream>>>(t2w, WT2h, WT2l, D_MODEL, 0, 0, D_MODEL);
  gemm2_kernel<2,true,false><<<dim3(16,32),256,0,stream>>>(
      PREVh, PREVl, WT1h, WT1l, t1b, nullptr, nullptr, nullptr, nullptr, nullptr,
      A1h, A1l, NTOK, D_MODEL, D_MODEL);
  gemm2_kernel<1,false,false><<<dim3(16,32),256,0,stream>>>(
      A1h, A1l, WT2h, WT2l, t2b, nullptr, nullptr, nullptr, nullptr, nullptr,
      PREDf, nullptr, NTOK, D_MODEL, D_MODEL);
  // 10) losses / routers
  err_kernel<<<NTOK, 256, 0, stream>>>(PREDf, out, x_in, ERRf);
  stats_kernel<<<1, 1024, 0, stream>>>(ERRf, out);
  cscore_kernel<<<NTOK, 256, 0, stream>>>(x_in, rw, rb, CSf, out + OFF_CP);
  closs_kernel<<<1, 1024, 0, stream>>>(CSf, out + OFF_B, out + OFF_CL);
}

// Round 11
// 3129.585 us; speedup vs baseline: 1.0112x; 1.0010x over previous
//
#include <hip/hip_runtime.h>
#include <math.h>

#define B_SZ 2
#define T_SEQ 2048
#define D_MODEL 2048
#define NHEAD 16
#define HDIM 128
#define FFN 8192
#define NTOK (B_SZ*T_SEQ)   // 4096

// d_out layout (fp32): x_posterior | tpn_loss | causal_loss | g | binary | probs
#define OFF_TPN 8388608
#define OFF_CL  8388609
#define OFF_G   8388610
#define OFF_B   8392706
#define OFF_CP  8396802

#define RLO 1024.0f
#define RLOI 9.765625e-4f   // 1/1024

typedef __attribute__((ext_vector_type(8))) _Float16 f16x8;
typedef __attribute__((ext_vector_type(4))) float f32x4;
typedef unsigned int u32;
typedef const u32 __attribute__((address_space(1)))* gas_p;
typedef u32 __attribute__((address_space(3)))* las_p;

__device__ __forceinline__ void gload16(const _Float16* g, _Float16* l) {
  __builtin_amdgcn_global_load_lds((gas_p)g, (las_p)l, 16, 0, 0);
}
__device__ __forceinline__ f16x8 ld8h(const _Float16* p) {
  return *reinterpret_cast<const f16x8*>(p);
}
__device__ __forceinline__ f32x4 mfma16h(f16x8 a, f16x8 b, f32x4 c) {
  return __builtin_amdgcn_mfma_f32_16x16x32_f16(a, b, c, 0, 0, 0);
}
__device__ __forceinline__ f32x4 zero4() { f32x4 z = {0.f,0.f,0.f,0.f}; return z; }
__device__ __forceinline__ float wredsum(float v) {
  #pragma unroll
  for (int d = 1; d < 64; d <<= 1) v += __shfl_xor(v, d, 64);
  return v;
}
__device__ __forceinline__ void split1(float v, _Float16& h, _Float16& l) {
  _Float16 hh = (_Float16)v;
  h = hh;
  l = (_Float16)((v - (float)hh) * RLO);
}

// ---- weight sub-panel transpose + fp16 split ----
// dst[c][r] (c<C, r<R, dst row stride R) = split(src[(r0+r)*srcStride + c0+c])
__global__ __launch_bounds__(256) void wsplit_kernel(const float* __restrict__ src,
                                                     _Float16* __restrict__ dhi,
                                                     _Float16* __restrict__ dlo,
                                                     int srcStride, int r0, int c0,
                                                     int R) {
  __shared__ float tile[32][33];
  int cb = blockIdx.x * 32, rb = blockIdx.y * 32;
  int tx = threadIdx.x, ty = threadIdx.y;
  #pragma unroll
  for (int i = 0; i < 4; ++i)
    tile[ty + i*8][tx] = src[(size_t)(r0 + rb + ty + i*8) * srcStride + c0 + cb + tx];
  __syncthreads();
  #pragma unroll
  for (int i = 0; i < 4; ++i) {
    float v = tile[tx][ty + i*8];
    _Float16 h, l; split1(v, h, l);
    size_t idx = (size_t)(cb + ty + i*8) * R + rb + tx;
    dhi[idx] = h; dlo[idx] = l;
  }
}

// ---- RMSNorm: fp32 in -> f16 pair out ----
__global__ __launch_bounds__(256) void rmsnorm_kernel(const float* __restrict__ x,
                                                      const float* __restrict__ wgt,
                                                      _Float16* __restrict__ oh,
                                                      _Float16* __restrict__ ol) {
  const int row = blockIdx.x, tid = threadIdx.x;
  const float* xr = x + (size_t)row * D_MODEL;
  float4 v0 = *(const float4*)(xr + tid*8);
  float4 v1 = *(const float4*)(xr + tid*8 + 4);
  float ss = v0.x*v0.x + v0.y*v0.y + v0.z*v0.z + v0.w*v0.w
           + v1.x*v1.x + v1.y*v1.y + v1.z*v1.z + v1.w*v1.w;
  ss = wredsum(ss);
  __shared__ float red[4];
  if ((tid & 63) == 0) red[tid >> 6] = ss;
  __syncthreads();
  float tot = red[0] + red[1] + red[2] + red[3];
  float inv = 1.f / sqrtf(tot / (float)D_MODEL + 1e-6f);
  float4 w0 = *(const float4*)(wgt + tid*8);
  float4 w1 = *(const float4*)(wgt + tid*8 + 4);
  float f[8];
  f[0]=v0.x*inv*w0.x; f[1]=v0.y*inv*w0.y; f[2]=v0.z*inv*w0.z; f[3]=v0.w*inv*w0.w;
  f[4]=v1.x*inv*w1.x; f[5]=v1.y*inv*w1.y; f[6]=v1.z*inv*w1.z; f[7]=v1.w*inv*w1.w;
  f16x8 hh, ll;
  #pragma unroll
  for (int i = 0; i < 8; ++i) { _Float16 h, l; split1(f[i], h, l); hh[i]=h; ll[i]=l; }
  *(f16x8*)(oh + (size_t)row * D_MODEL + tid*8) = hh;
  *(f16x8*)(ol + (size_t)row * D_MODEL + tid*8) = ll;
}

// ---- all-pair GEMM: C[M][N] = (Ah+Al/1024)[M][K] @ (Bh+Bl/1024)[N][K]^T ----
// 128x128 tile, BK=32, 4 waves 2x2, 3x mfma_f32_16x16x32_f16 per frag pair.
// Double-buffered LDS (64 KiB) + cross-step prefetch (T3-minimum).
// Tile order: grouped (GROUP_M=8) then XCD-chunked -> supertile L2 reuse.
// Staging: global_load_lds width-16, 16B chunks XOR-swizzled on BOTH sides.
// MODE: 0 plain, 1 +bias, 2 silu(v+bias), 3 +resid, 4 silu(g)*v (g pair)
// QKV: blockIdx.z selects Q/K/V; V is written TRANSPOSED to [b*h][d][T].
template<int MODE, bool OUT_SPLIT, bool QKV>
__global__ __launch_bounds__(256) void gemm2_kernel(
    const _Float16* __restrict__ Ahi, const _Float16* __restrict__ Alo,
    const _Float16* __restrict__ Bhi, const _Float16* __restrict__ Blo,
    const float* __restrict__ b0, const float* __restrict__ b1,
    const float* __restrict__ b2, const float* __restrict__ resid,
    const _Float16* __restrict__ ghi, const _Float16* __restrict__ glo,
    void* __restrict__ C1, void* __restrict__ C2,
    int M, int N, int K) {
  // grouped + XCD-chunked tile order (nbm always a multiple of 8 here)
  const int nbn = gridDim.x, nbm = gridDim.y;
  int bid = blockIdx.y * nbn + blockIdx.x;
  bid = (bid & 7) * ((nbn * nbm) >> 3) + (bid >> 3);   // XCD chunking
  const int nig = nbn << 3;
  const int gid = bid / nig, rem = bid - gid * nig;
  const int by = (gid << 3) + (rem & 7);
  const int bx = rem >> 3;
  int sel = 0;
  const float* bias = b0;
  size_t cbase = 0, bwoff = 0;
  if (QKV) {
    sel = blockIdx.z;
    bias = (sel == 0) ? b0 : ((sel == 1) ? b1 : b2);
    bwoff = (size_t)sel * D_MODEL * D_MODEL;
    cbase = (size_t)sel * (size_t)NTOK * D_MODEL;
  }
  const int n0 = bx * 128, m0 = by * 128;
  const int tid = threadIdx.x, lane = tid & 63, wv = tid >> 6;
  const int wr = wv >> 1, wc = wv & 1;
  const int l16 = lane & 15, lg = lane >> 4;
  // [buf][arr][128][32] halves; arr: 0=Ah 1=Al 2=Bh 3=Bl
  __shared__ _Float16 SH[2 * 4 * 128 * 32];
  f32x4 acc1[4][4], acc2[4][4];
  #pragma unroll
  for (int i = 0; i < 4; ++i)
    #pragma unroll
    for (int j = 0; j < 4; ++j) { acc1[i][j] = zero4(); acc2[i][j] = zero4(); }
  // staging: wave wv covers rows [wv*32, wv*32+32); 2 issues of 16 rows/array.
  const int srow = wv * 32 + (lane >> 2);
  const int scol = ((lane & 3) ^ ((lane >> 2) & 3)) * 8;
  const _Float16* ga0  = Ahi + (size_t)(m0 + srow) * K + scol;
  const _Float16* ga1  = ga0 + (size_t)16 * K;
  const _Float16* gal0 = Alo + (size_t)(m0 + srow) * K + scol;
  const _Float16* gal1 = gal0 + (size_t)16 * K;
  const _Float16* gb0  = Bhi + bwoff + (size_t)(n0 + srow) * K + scol;
  const _Float16* gb1  = gb0 + (size_t)16 * K;
  const _Float16* gbl0 = Blo + bwoff + (size_t)(n0 + srow) * K + scol;
  const _Float16* gbl1 = gbl0 + (size_t)16 * K;
  const int dbase = wv * 32 * 32;          // element offset within array
  const int csw = (lg ^ (l16 & 3)) * 8;    // swizzled read chunk offset

  #define STAGE(buf, kk) do {                                   \
    _Float16* sb = SH + (buf) * 16384;                          \
    gload16(ga0  + (kk), sb          + dbase);                  \
    gload16(ga1  + (kk), sb          + dbase + 512);            \
    gload16(gal0 + (kk), sb + 4096  + dbase);                   \
    gload16(gal1 + (kk), sb + 4096  + dbase + 512);             \
    gload16(gb0  + (kk), sb + 8192  + dbase);                   \
    gload16(gb1  + (kk), sb + 8192  + dbase + 512);             \
    gload16(gbl0 + (kk), sb + 12288 + dbase);                   \
    gload16(gbl1 + (kk), sb + 12288 + dbase + 512);             \
  } while (0)

  int cur = 0;
  STAGE(0, 0);
  __syncthreads();
  for (int kk = 0; kk < K; kk += 32) {
    if (kk + 32 < K) STAGE(cur ^ 1, kk + 32);   // prefetch next step
    const _Float16* sb = SH + cur * 16384;
    f16x8 af_h[4], af_l[4];
    #pragma unroll
    for (int i = 0; i < 4; ++i) {
      const int off = (wr*64 + i*16 + l16) * 32 + csw;
      af_h[i] = ld8h(sb + off);
      af_l[i] = ld8h(sb + 4096 + off);
    }
    #pragma unroll
    for (int j = 0; j < 4; ++j) {
      const int offb = (wc*64 + j*16 + l16) * 32 + csw;
      f16x8 bh = ld8h(sb + 8192 + offb);
      f16x8 bl = ld8h(sb + 12288 + offb);
      #pragma unroll
      for (int i = 0; i < 4; ++i) {
        acc1[i][j] = mfma16h(af_h[i], bh, acc1[i][j]);
        acc2[i][j] = mfma16h(af_h[i], bl, acc2[i][j]);
        acc2[i][j] = mfma16h(af_l[i], bh, acc2[i][j]);
      }
    }
    __syncthreads();   // drains prefetch vmcnt + publishes buf^1
    cur ^= 1;
  }
  #undef STAGE
  #pragma unroll
  for (int i = 0; i < 4; ++i) {
    const int row0 = m0 + wr*64 + i*16 + lg*4;   // D: row=(lane>>4)*4+t, col=lane&15
    #pragma unroll
    for (int j = 0; j < 4; ++j) {
      const int col = n0 + wc*64 + j*16 + l16;
      float bv = (MODE == 1 || MODE == 2) ? bias[col] : 0.f;
      #pragma unroll
      for (int t = 0; t < 4; ++t) {
        const int row = row0 + t;
        size_t idx;
        if (QKV && sel == 2)   // V -> transposed [b*h][d][T] layout
          idx = cbase + (size_t)(row >> 11) * ((size_t)D_MODEL * T_SEQ)
                      + (size_t)col * T_SEQ + (row & (T_SEQ - 1));
        else
          idx = cbase + (size_t)row * N + col;
        float v = acc1[i][j][t] + acc2[i][j][t] * RLOI + bv;
        if (MODE == 2) v = v / (1.f + __expf(-v));
        if (MODE == 3) v += resid[idx];
        if (MODE == 4) {
          float g = (float)ghi[idx] + (float)glo[idx] * RLOI;
          v = g / (1.f + __expf(-g)) * v;
        }
        if (OUT_SPLIT) {
          _Float16 h, l; split1(v, h, l);
          ((_Float16*)C1)[idx] = h;
          ((_Float16*)C2)[idx] = l;
        } else {
          ((float*)C1)[idx] = v;
        }
      }
    }
  }
}

// ---- RoPE (neox), in place on f16 pairs; one token-row per block ----
__global__ __launch_bounds__(256) void rope_kernel(_Float16* __restrict__ Qh,
                                                   _Float16* __restrict__ Ql,
                                                   _Float16* __restrict__ Kh,
                                                   _Float16* __restrict__ Kl) {
  const int row = blockIdx.x;
  const int tpos = row & (T_SEQ - 1);
  __shared__ float svs[64], cvs[64];
  if (threadIdx.x < 64) {
    double invf = exp(-(double)threadIdx.x * (9.210340371976184 / 64.0));
    double ph = fmod((double)tpos * invf, 6.283185307179586476925);
    sincosf((float)ph, &svs[threadIdx.x], &cvs[threadIdx.x]);
  }
  __syncthreads();
  for (int item = threadIdx.x; item < NHEAD * 64; item += 256) {
    const int h = item >> 6, d = item & 63;
    const float sv = svs[d], cv = cvs[d];
    const size_t i0 = (size_t)row * D_MODEL + h*HDIM + d;
    const size_t i1 = i0 + 64;
    float q0 = (float)Qh[i0] + (float)Ql[i0]*RLOI;
    float q1 = (float)Qh[i1] + (float)Ql[i1]*RLOI;
    float k0 = (float)Kh[i0] + (float)Kl[i0]*RLOI;
    float k1 = (float)Kh[i1] + (float)Kl[i1]*RLOI;
    _Float16 hh, ll;
    split1(q0*cv - q1*sv, hh, ll); Qh[i0]=hh; Ql[i0]=ll;
    split1(q1*cv + q0*sv, hh, ll); Qh[i1]=hh; Ql[i1]=ll;
    split1(k0*cv - k1*sv, hh, ll); Kh[i0]=hh; Kl[i0]=ll;
    split1(k1*cv + k0*sv, hh, ll); Kh[i1]=hh; Kl[i1]=ll;
  }
}

// ---- flash attention on pairs: 64 q-rows/block, KV tiles of 32 ----
// R7-proven structure: K staged via global_load_lds into [32][128] with
// chunk^(row&7) XOR swizzle (source + ds_read side); V pre-transposed in
// global ([b*h][d][T]) and DMA-staged linearly into [128][32].
// __launch_bounds__(256,4) pins VGPR <=128: R10 showed inlined __expf pushes
// the allocator to 136 VGPR -> occupancy cliff (m69: waves halve at 128).
__global__ __launch_bounds__(256, 4) void attn_kernel(
    const _Float16* __restrict__ Qh, const _Float16* __restrict__ Ql,
    const _Float16* __restrict__ Kh, const _Float16* __restrict__ Kl,
    const _Float16* __restrict__ VTh, const _Float16* __restrict__ VTl,
    _Float16* __restrict__ Oh, _Float16* __restrict__ Ol) {
  const int qb = (int)gridDim.x - 1 - (int)blockIdx.x;  // heavy blocks first
  const int bhid = blockIdx.y;
  const int b = bhid >> 4, h = bhid & 15;
  const int tid = threadIdx.x, lane = tid & 63, w = tid >> 6;
  const int l16 = lane & 15, lg = lane >> 4;
  __shared__ _Float16 Ksh[32][128], Ksl[32][128];
  __shared__ _Float16 Vth[128][32], Vtl[128][32];
  __shared__ _Float16 Psh[4][16][40], Psl[4][16][40];
  const size_t hbase  = (size_t)b * T_SEQ * D_MODEL + (size_t)h * HDIM;
  const size_t vtbase = (size_t)bhid * (size_t)HDIM * T_SEQ;
  const size_t qrow0 = (size_t)qb * 64;

  f16x8 qf_h[4], qf_l[4];
  {
    const size_t qoff = hbase + (qrow0 + w*16 + l16) * D_MODEL + lg*8;
    #pragma unroll
    for (int c = 0; c < 4; ++c) {
      qf_h[c] = ld8h(Qh + qoff + c*32);
      qf_l[c] = ld8h(Ql + qoff + c*32);
    }
  }
  f32x4 acc1[8], acc2[8];
  #pragma unroll
  for (int df = 0; df < 8; ++df) { acc1[df] = zero4(); acc2[df] = zero4(); }
  float mrow[4] = {-3e38f,-3e38f,-3e38f,-3e38f};
  float drow[4] = {0.f,0.f,0.f,0.f};

  // staging pointers (DMA; K source chunk-XOR-swizzled, V^T linear)
  const int krow = w*8 + (lane >> 4);
  const int kch0 = ((lane & 15) ^ (krow & 7)) * 8;
  const int kch1 = ((lane & 15) ^ ((krow + 4) & 7)) * 8;
  const _Float16* gkh0 = Kh + hbase + (size_t)krow * D_MODEL + kch0;
  const _Float16* gkh1 = Kh + hbase + (size_t)(krow + 4) * D_MODEL + kch1;
  const _Float16* gkl0 = Kl + hbase + (size_t)krow * D_MODEL + kch0;
  const _Float16* gkl1 = Kl + hbase + (size_t)(krow + 4) * D_MODEL + kch1;
  _Float16* dkh0 = &Ksh[w*8][0];   _Float16* dkh1 = &Ksh[w*8+4][0];
  _Float16* dkl0 = &Ksl[w*8][0];   _Float16* dkl1 = &Ksl[w*8+4][0];
  const int vrow = w*32 + (lane >> 2);
  const int vcol = (lane & 3) * 8;
  const _Float16* gvh0 = VTh + vtbase + (size_t)vrow * T_SEQ + vcol;
  const _Float16* gvh1 = gvh0 + (size_t)16 * T_SEQ;
  const _Float16* gvl0 = VTl + vtbase + (size_t)vrow * T_SEQ + vcol;
  const _Float16* gvl1 = gvl0 + (size_t)16 * T_SEQ;
  _Float16* dvh0 = &Vth[w*32][0];  _Float16* dvh1 = &Vth[w*32+16][0];
  _Float16* dvl0 = &Vtl[w*32][0];  _Float16* dvl1 = &Vtl[w*32+16][0];

  const int nkb = (qb + 1) * 2;
  const float scale = 0.088388347648318447f;  // 1/sqrt(128)

  for (int kb = 0; kb < nkb; ++kb) {
    __syncthreads();
    const size_t ko = (size_t)kb * 32 * D_MODEL;
    const size_t vo = (size_t)kb * 32;
    gload16(gkh0 + ko, dkh0);  gload16(gkh1 + ko, dkh1);
    gload16(gkl0 + ko, dkl0);  gload16(gkl1 + ko, dkl1);
    gload16(gvh0 + vo, dvh0);  gload16(gvh1 + vo, dvh1);
    gload16(gvl0 + vo, dvl0);  gload16(gvl1 + vo, dvl1);
    __syncthreads();

    f32x4 s0 = zero4(), s0x = zero4(), s1 = zero4(), s1x = zero4();
    #pragma unroll
    for (int c = 0; c < 4; ++c) {
      const int pk = ((4*c + lg) ^ (l16 & 7)) * 8;
      f16x8 kh0 = ld8h(&Ksh[l16][pk]);
      f16x8 kl0 = ld8h(&Ksl[l16][pk]);
      f16x8 kh1 = ld8h(&Ksh[16 + l16][pk]);
      f16x8 kl1 = ld8h(&Ksl[16 + l16][pk]);
      s0  = mfma16h(qf_h[c], kh0, s0);
      s0x = mfma16h(qf_h[c], kl0, s0x);
      s0x = mfma16h(qf_l[c], kh0, s0x);
      s1  = mfma16h(qf_h[c], kh1, s1);
      s1x = mfma16h(qf_h[c], kl1, s1x);
      s1x = mfma16h(qf_l[c], kh1, s1x);
    }

    float p0[4], p1[4], corrv[4];
    #pragma unroll
    for (int t = 0; t < 4; ++t) {
      int qrow = qb*64 + w*16 + lg*4 + t;
      float a  = (s0[t] + s0x[t] * RLOI) * scale;
      float bb = (s1[t] + s1x[t] * RLOI) * scale;
      if (kb*32      + l16 > qrow) a  = -1e9f;
      if (kb*32 + 16 + l16 > qrow) bb = -1e9f;
      float mx = fmaxf(a, bb);
      #pragma unroll
      for (int d = 1; d < 16; d <<= 1) mx = fmaxf(mx, __shfl_xor(mx, d, 64));
      float mnew = fmaxf(mrow[t], mx);
      float corr = __expf(mrow[t] - mnew);
      float e0 = __expf(a - mnew), e1 = __expf(bb - mnew);
      float ps = e0 + e1;
      #pragma unroll
      for (int d = 1; d < 16; d <<= 1) ps += __shfl_xor(ps, d, 64);
      drow[t] = drow[t] * corr + ps;
      mrow[t] = mnew;
      corrv[t] = corr;
      p0[t] = e0; p1[t] = e1;
    }
    #pragma unroll
    for (int df = 0; df < 8; ++df)
      #pragma unroll
      for (int t = 0; t < 4; ++t) { acc1[df][t] *= corrv[t]; acc2[df][t] *= corrv[t]; }

    // P (D-layout) -> per-wave LDS -> reload in A-frag layout (split pair).
    #pragma unroll
    for (int t = 0; t < 4; ++t) {
      _Float16 hh, ll;
      split1(p0[t], hh, ll);
      Psh[w][lg*4 + t][l16] = hh;  Psl[w][lg*4 + t][l16] = ll;
      split1(p1[t], hh, ll);
      Psh[w][lg*4 + t][16 + l16] = hh;  Psl[w][lg*4 + t][16 + l16] = ll;
    }
    asm volatile("s_waitcnt lgkmcnt(0)" ::: "memory");
    __builtin_amdgcn_sched_barrier(0);
    f16x8 pf_h = ld8h(&Psh[w][l16][lg*8]);
    f16x8 pf_l = ld8h(&Psl[w][l16][lg*8]);
    #pragma unroll
    for (int df = 0; df < 8; ++df) {
      f16x8 vh = ld8h(&Vth[df*16 + l16][lg*8]);
      f16x8 vl = ld8h(&Vtl[df*16 + l16][lg*8]);
      acc1[df] = mfma16h(pf_h, vh, acc1[df]);
      acc2[df] = mfma16h(pf_h, vl, acc2[df]);
      acc2[df] = mfma16h(pf_l, vh, acc2[df]);
    }
  }
  #pragma unroll
  for (int df = 0; df < 8; ++df)
    #pragma unroll
    for (int t = 0; t < 4; ++t) {
      float o = (acc1[df][t] + acc2[df][t] * RLOI) / drow[t];
      _Float16 hh, ll; split1(o, hh, ll);
      const size_t oo = hbase + (qrow0 + w*16 + lg*4 + t) * D_MODEL + df*16 + l16;
      Oh[oo] = hh; Ol[oo] = ll;
    }
}

// ---- prev pair: t==0 ? 0 : split(x_post[b,t-1,:]) ----
__global__ __launch_bounds__(256) void shiftprev_kernel(const float* __restrict__ xpost,
                                                        _Float16* __restrict__ ph,
                                                        _Float16* __restrict__ pl) {
  const int row = blockIdx.x;
  const int tpos = row & (T_SEQ - 1);
  const size_t o = (size_t)row * D_MODEL + threadIdx.x * 8;
  f16x8 hh, ll;
  if (tpos == 0) {
    #pragma unroll
    for (int i = 0; i < 8; ++i) { hh[i] = (_Float16)0.f; ll[i] = (_Float16)0.f; }
  } else {
    const float* src = xpost + o - D_MODEL;
    #pragma unroll
    for (int i = 0; i < 8; ++i) {
      _Float16 h, l; split1(src[i], h, l); hh[i] = h; ll[i] = l;
    }
  }
  *(f16x8*)(ph + o) = hh;
  *(f16x8*)(pl + o) = ll;
}

// ---- per-row err = mean_D (pred - (xpost - xorig))^2 ----
__global__ __launch_bounds__(256) void err_kernel(const float* __restrict__ pred,
                                                  const float* __restrict__ xpost,
                                                  const float* __restrict__ xorig,
                                                  float* __restrict__ err) {
  const int row = blockIdx.x, tid = threadIdx.x;
  const size_t base = (size_t)row * D_MODEL + tid * 8;
  const float* pp = pred + base;
  const float* ap = xpost + base;
  const float* op = xorig + base;
  float ss = 0.f;
  #pragma unroll
  for (int i = 0; i < 8; ++i) {
    float d = pp[i] - (ap[i] - op[i]);
    ss += d * d;
  }
  ss = wredsum(ss);
  __shared__ float red[4];
  if ((tid & 63) == 0) red[tid >> 6] = ss;
  __syncthreads();
  if (tid == 0) err[row] = (red[0]+red[1]+red[2]+red[3]) / (float)D_MODEL;
}

// ---- stats: mean/std of err -> tpn_loss, g_continuous, binary_targets ----
__global__ __launch_bounds__(1024) void stats_kernel(const float* __restrict__ err,
                                                     float* __restrict__ dout) {
  __shared__ float red[16];
  __shared__ float sh[2];
  const int tid = threadIdx.x;
  float s = 0.f;
  for (int i = tid; i < NTOK; i += 1024) s += err[i];
  s = wredsum(s);
  if ((tid & 63) == 0) red[tid >> 6] = s;
  __syncthreads();
  if (tid == 0) {
    float t = 0.f;
    for (int i = 0; i < 16; ++i) t += red[i];
    sh[0] = t / (float)NTOK;
  }
  __syncthreads();
  const float mean = sh[0];
  float v = 0.f;
  for (int i = tid; i < NTOK; i += 1024) { float d = err[i] - mean; v += d * d; }
  v = wredsum(v);
  __syncthreads();
  if ((tid & 63) == 0) red[tid >> 6] = v;
  __syncthreads();
  if (tid == 0) {
    float t = 0.f;
    for (int i = 0; i < 16; ++i) t += red[i];
    sh[1] = sqrtf(t / (float)NTOK);
    dout[OFF_TPN] = mean;   // tpn_loss == mean(err)
  }
  __syncthreads();
  const float stdv = sh[1];
  for (int i = tid; i < NTOK; i += 1024) {
    float z = (err[i] - mean) / (stdv + 1e-6f);
    dout[OFF_G + i] = 1.f / (1.f + expf(-z));
    dout[OFF_B + i] = (err[i] > mean) ? 1.f : 0.f;
  }
}

// ---- causal router scores/probs ----
__global__ __launch_bounds__(256) void cscore_kernel(const float* __restrict__ x,
                                                     const float* __restrict__ rwv,
                                                     const float* __restrict__ rbv,
                                                     float* __restrict__ cs,
                                                     float* __restrict__ probs) {
  const int row = blockIdx.x, tid = threadIdx.x;
  const float* xr = x + (size_t)row * D_MODEL + tid * 8;
  const float* wr = rwv + tid * 8;
  float s = 0.f;
  #pragma unroll
  for (int i = 0; i < 8; ++i) s += xr[i] * wr[i];
  s = wredsum(s);
  __shared__ float red[4];
  if ((tid & 63) == 0) red[tid >> 6] = s;
  __syncthreads();
  if (tid == 0) {
    float v = red[0]+red[1]+red[2]+red[3] + rbv[0];
    cs[row] = v;
    probs[row] = 1.f / (1.f + expf(-v));
  }
}

// ---- BCE-with-logits ----
__global__ __launch_bounds__(1024) void closs_kernel(const float* __restrict__ cs,
                                                     const float* __restrict__ tgt,
                                                     float* __restrict__ outv) {
  __shared__ float red[16];
  const int tid = threadIdx.x;
  float a = 0.f;
  for (int i = tid; i < NTOK; i += 1024) {
    float s = cs[i], t = tgt[i];
    a += fmaxf(s, 0.f) - s * t + log1pf(expf(-fabsf(s)));
  }
  a = wredsum(a);
  if ((tid & 63) == 0) red[tid >> 6] = a;
  __syncthreads();
  if (tid == 0) {
    float t = 0.f;
    for (int i = 0; i < 16; ++i) t += red[i];
    outv[0] = t / (float)NTOK;
  }
}

extern "C" void kernel_launch(void* const* d_in, const int* in_sizes, int n_in,
                              void* d_out, int out_size, void* d_ws, size_t ws_size,
                              hipStream_t stream) {
  (void)in_sizes; (void)n_in; (void)out_size; (void)ws_size;
  const float* x_in = (const float*)d_in[0];
  const float* q_w  = (const float*)d_in[1];
  const float* q_b  = (const float*)d_in[2];
  const float* k_w  = (const float*)d_in[3];
  const float* k_b  = (const float*)d_in[4];
  const float* v_w  = (const float*)d_in[5];
  const float* v_b  = (const float*)d_in[6];
  const float* o_w  = (const float*)d_in[7];
  const float* ln1  = (const float*)d_in[8];
  const float* ln2  = (const float*)d_in[9];
  const float* gw   = (const float*)d_in[10];
  const float* uw   = (const float*)d_in[11];
  const float* dw   = (const float*)d_in[12];
  const float* t1w  = (const float*)d_in[13];
  const float* t1b  = (const float*)d_in[14];
  const float* t2w  = (const float*)d_in[15];
  const float* t2b  = (const float*)d_in[16];
  const float* rw   = (const float*)d_in[17];
  const float* rb   = (const float*)d_in[18];
  float* out = (float*)d_out;
  char* ws = (char*)d_ws;

  // -------- workspace plan, peak 208 MiB (proven-safe envelope) --------
  _Float16* WQKVh = (_Float16*)(ws + 0);           // 3x [2048][2048]
  _Float16* WQKVl = (_Float16*)(ws + 25165824);
  _Float16* WOh   = (_Float16*)(ws + 0);
  _Float16* WOl   = (_Float16*)(ws + 8388608);
  _Float16* WDh   = (_Float16*)(ws + 0);           // [2048][4096] half
  _Float16* WDl   = (_Float16*)(ws + 16777216);
  _Float16* WT1h  = (_Float16*)(ws + 0);
  _Float16* WT1l  = (_Float16*)(ws + 8388608);
  _Float16* WT2h  = (_Float16*)(ws + 16777216);
  _Float16* WT2l  = (_Float16*)(ws + 25165824);
  _Float16* Hh    = (_Float16*)(ws + 50331648);
  _Float16* Hl    = (_Float16*)(ws + 67108864);
  _Float16* PREVh = Hh;
  _Float16* PREVl = Hl;
  _Float16* QKVh  = (_Float16*)(ws + 83886080);    // [3][4096][2048]; V part is VT
  _Float16* QKVl  = (_Float16*)(ws + 134217728);
  _Float16* CTXh  = (_Float16*)(ws + 184549376);
  _Float16* CTXl  = (_Float16*)(ws + 201326592);   // ends 218103808 (208 MiB)
  _Float16* WGh   = (_Float16*)(ws + 83886080);    // [4096][2048] half
  _Float16* WGl   = (_Float16*)(ws + 100663296);
  _Float16* WUh   = (_Float16*)(ws + 117440512);
  _Float16* WUl   = (_Float16*)(ws + 134217728);
  _Float16* MLPh  = (_Float16*)(ws + 150994944);   // [4096][4096] half
  _Float16* MLPl  = (_Float16*)(ws + 184549376);   // ends 218103808
  _Float16* A1h   = (_Float16*)(ws + 83886080);
  _Float16* A1l   = (_Float16*)(ws + 100663296);
  float*    PREDf = (float*)   (ws + 117440512);   // 32 MiB, ends 150994944
  float*    ERRf  = (float*)   (ws + 150994944);
  float*    CSf   = (float*)   (ws + 151011328);

  const size_t DD = (size_t)D_MODEL * D_MODEL;
  const size_t TD = (size_t)NTOK * D_MODEL;
  dim3 tb(32, 8);
  const dim3 gW22(64, 64);     // [2048]x[2048] split
  const dim3 gWg(128, 64);     // gw/uw half: C=4096, R=2048
  const dim3 gWd(64, 128);     // dw half:    C=2048, R=4096

  // 1) QKV weights -> A
  wsplit_kernel<<<gW22, tb, 0, stream>>>(q_w, WQKVh,        WQKVl,        D_MODEL, 0, 0, D_MODEL);
  wsplit_kernel<<<gW22, tb, 0, stream>>>(k_w, WQKVh + DD,   WQKVl + DD,   D_MODEL, 0, 0, D_MODEL);
  wsplit_kernel<<<gW22, tb, 0, stream>>>(v_w, WQKVh + 2*DD, WQKVl + 2*DD, D_MODEL, 0, 0, D_MODEL);
  // 2) h = rmsnorm(x, ln1) -> B
  rmsnorm_kernel<<<NTOK, 256, 0, stream>>>(x_in, ln1, Hh, Hl);
  // 3) fused QKV GEMM -> C (z selects Q/K/V; V written transposed [b*h][d][T])
  gemm2_kernel<1,true,true><<<dim3(16,32,3),256,0,stream>>>(
      Hh, Hl, WQKVh, WQKVl, q_b, k_b, v_b, nullptr, nullptr, nullptr,
      QKVh, QKVl, NTOK, D_MODEL, D_MODEL);
  // 4) RoPE in place on Q,K
  rope_kernel<<<NTOK, 256, 0, stream>>>(QKVh, QKVl, QKVh + TD, QKVl + TD);
  // 5) attention -> D (CTX)
  attn_kernel<<<dim3(T_SEQ/64, B_SZ*NHEAD), 256, 0, stream>>>(
      QKVh, QKVl, QKVh + TD, QKVl + TD, QKVh + 2*TD, QKVl + 2*TD, CTXh, CTXl);
  // 6) o_w -> A; x = x_in + ctx @ o_w -> out
  wsplit_kernel<<<gW22, tb, 0, stream>>>(o_w, WOh, WOl, D_MODEL, 0, 0, D_MODEL);
  gemm2_kernel<3,false,false><<<dim3(16,32),256,0,stream>>>(
      CTXh, CTXl, WOh, WOl, nullptr, nullptr, nullptr, x_in, nullptr, nullptr,
      out, nullptr, NTOK, D_MODEL, D_MODEL);
  // 7) h2 = rmsnorm(x, ln2) -> B
  rmsnorm_kernel<<<NTOK, 256, 0, stream>>>(out, ln2, Hh, Hl);
  // 8) FFN in two halves of F; down accumulates into out (split-K, fp32)
  for (int half = 0; half < 2; ++half) {
    const int f0 = half * (FFN/2);
    wsplit_kernel<<<gWg, tb, 0, stream>>>(gw, WGh, WGl, FFN, 0, f0, D_MODEL);
    wsplit_kernel<<<gWg, tb, 0, stream>>>(uw, WUh, WUl, FFN, 0, f0, D_MODEL);
    gemm2_kernel<0,true,false><<<dim3(32,32),256,0,stream>>>(
        Hh, Hl, WGh, WGl, nullptr, nullptr, nullptr, nullptr, nullptr, nullptr,
        MLPh, MLPl, NTOK, FFN/2, D_MODEL);
    gemm2_kernel<4,true,false><<<dim3(32,32),256,0,stream>>>(
        Hh, Hl, WUh, WUl, nullptr, nullptr, nullptr, nullptr, MLPh, MLPl,
        MLPh, MLPl, NTOK, FFN/2, D_MODEL);
    wsplit_kernel<<<gWd, tb, 0, stream>>>(dw, WDh, WDl, D_MODEL, f0, 0, FFN/2);
    gemm2_kernel<3,false,false><<<dim3(16,32),256,0,stream>>>(
        MLPh, MLPl, WDh, WDl, nullptr, nullptr, nullptr, out, nullptr, nullptr,
        out, nullptr, NTOK, D_MODEL, FFN/2);
  }
  // 9) TPN
  shiftprev_kernel<<<NTOK, 256, 0, stream>>>(out, PREVh, PREVl);
  wsplit_kernel<<<gW22, tb, 0, stream>>>(t1w, WT1h, WT1l, D_MODEL, 0, 0, D_MODEL);
  wsplit_kernel<<<gW22, tb, 0, stream>>>(t2w, WT2h, WT2l, D_MODEL, 0, 0, D_MODEL);
  gemm2_kernel<2,true,false><<<dim3(16,32),256,0,stream>>>(
      PREVh, PREVl, WT1h, WT1l, t1b, nullptr, nullptr, nullptr, nullptr, nullptr,
      A1h, A1l, NTOK, D_MODEL, D_MODEL);
  gemm2_kernel<1,false,false><<<dim3(16,32),256,0,stream>>>(
      A1h, A1l, WT2h, WT2l, t2b, nullptr, nullptr, nullptr, nullptr, nullptr,
      PREDf, nullptr, NTOK, D_MODEL, D_MODEL);
  // 10) losses / routers
  err_kernel<<<NTOK, 256, 0, stream>>>(PREDf, out, x_in, ERRf);
  stats_kernel<<<1, 1024, 0, stream>>>(ERRf, out);
  cscore_kernel<<<NTOK, 256, 0, stream>>>(x_in, rw, rb, CSf, out + OFF_CP);
  closs_kernel<<<1, 1024, 0, stream>>>(CSf, out + OFF_B, out + OFF_CL);
}

// Round 12
// 2996.826 us; speedup vs baseline: 1.0560x; 1.0443x over previous
//
#include <hip/hip_runtime.h>
#include <math.h>

#define B_SZ 2
#define T_SEQ 2048
#define D_MODEL 2048
#define NHEAD 16
#define HDIM 128
#define FFN 8192
#define NTOK (B_SZ*T_SEQ)   // 4096

// d_out layout (fp32): x_posterior | tpn_loss | causal_loss | g | binary | probs
#define OFF_TPN 8388608
#define OFF_CL  8388609
#define OFF_G   8388610
#define OFF_B   8392706
#define OFF_CP  8396802

#define RLO 1024.0f
#define RLOI 9.765625e-4f   // 1/1024

typedef __attribute__((ext_vector_type(8))) _Float16 f16x8;
typedef __attribute__((ext_vector_type(4))) float f32x4;
typedef unsigned int u32;
typedef const u32 __attribute__((address_space(1)))* gas_p;
typedef u32 __attribute__((address_space(3)))* las_p;

__device__ __forceinline__ void gload16(const _Float16* g, _Float16* l) {
  __builtin_amdgcn_global_load_lds((gas_p)g, (las_p)l, 16, 0, 0);
}
__device__ __forceinline__ f16x8 ld8h(const _Float16* p) {
  return *reinterpret_cast<const f16x8*>(p);
}
__device__ __forceinline__ f32x4 mfma16h(f16x8 a, f16x8 b, f32x4 c) {
  return __builtin_amdgcn_mfma_f32_16x16x32_f16(a, b, c, 0, 0, 0);
}
__device__ __forceinline__ f32x4 zero4() { f32x4 z = {0.f,0.f,0.f,0.f}; return z; }
__device__ __forceinline__ float wredsum(float v) {
  #pragma unroll
  for (int d = 1; d < 64; d <<= 1) v += __shfl_xor(v, d, 64);
  return v;
}
__device__ __forceinline__ void split1(float v, _Float16& h, _Float16& l) {
  _Float16 hh = (_Float16)v;
  h = hh;
  l = (_Float16)((v - (float)hh) * RLO);
}

// ---- weight sub-panel transpose + fp16 split ----
// dst[c][r] (c<C, r<R, dst row stride R) = split(src[(r0+r)*srcStride + c0+c])
__global__ __launch_bounds__(256) void wsplit_kernel(const float* __restrict__ src,
                                                     _Float16* __restrict__ dhi,
                                                     _Float16* __restrict__ dlo,
                                                     int srcStride, int r0, int c0,
                                                     int R) {
  __shared__ float tile[32][33];
  int cb = blockIdx.x * 32, rb = blockIdx.y * 32;
  int tx = threadIdx.x, ty = threadIdx.y;
  #pragma unroll
  for (int i = 0; i < 4; ++i)
    tile[ty + i*8][tx] = src[(size_t)(r0 + rb + ty + i*8) * srcStride + c0 + cb + tx];
  __syncthreads();
  #pragma unroll
  for (int i = 0; i < 4; ++i) {
    float v = tile[tx][ty + i*8];
    _Float16 h, l; split1(v, h, l);
    size_t idx = (size_t)(cb + ty + i*8) * R + rb + tx;
    dhi[idx] = h; dlo[idx] = l;
  }
}

// ---- RMSNorm: fp32 in -> f16 pair out ----
__global__ __launch_bounds__(256) void rmsnorm_kernel(const float* __restrict__ x,
                                                      const float* __restrict__ wgt,
                                                      _Float16* __restrict__ oh,
                                                      _Float16* __restrict__ ol) {
  const int row = blockIdx.x, tid = threadIdx.x;
  const float* xr = x + (size_t)row * D_MODEL;
  float4 v0 = *(const float4*)(xr + tid*8);
  float4 v1 = *(const float4*)(xr + tid*8 + 4);
  float ss = v0.x*v0.x + v0.y*v0.y + v0.z*v0.z + v0.w*v0.w
           + v1.x*v1.x + v1.y*v1.y + v1.z*v1.z + v1.w*v1.w;
  ss = wredsum(ss);
  __shared__ float red[4];
  if ((tid & 63) == 0) red[tid >> 6] = ss;
  __syncthreads();
  float tot = red[0] + red[1] + red[2] + red[3];
  float inv = 1.f / sqrtf(tot / (float)D_MODEL + 1e-6f);
  float4 w0 = *(const float4*)(wgt + tid*8);
  float4 w1 = *(const float4*)(wgt + tid*8 + 4);
  float f[8];
  f[0]=v0.x*inv*w0.x; f[1]=v0.y*inv*w0.y; f[2]=v0.z*inv*w0.z; f[3]=v0.w*inv*w0.w;
  f[4]=v1.x*inv*w1.x; f[5]=v1.y*inv*w1.y; f[6]=v1.z*inv*w1.z; f[7]=v1.w*inv*w1.w;
  f16x8 hh, ll;
  #pragma unroll
  for (int i = 0; i < 8; ++i) { _Float16 h, l; split1(f[i], h, l); hh[i]=h; ll[i]=l; }
  *(f16x8*)(oh + (size_t)row * D_MODEL + tid*8) = hh;
  *(f16x8*)(ol + (size_t)row * D_MODEL + tid*8) = ll;
}

// ---- all-pair GEMM: C[M][N] = (Ah+Al/1024)[M][K] @ (Bh+Bl/1024)[N][K]^T ----
// 128x128 tile, BK=32, 4 waves 2x2, 3x mfma_f32_16x16x32_f16 per frag pair.
// Double-buffered LDS (64 KiB) + cross-step prefetch (T3-minimum).
// Tile order: grouped (GROUP_M=8) then XCD-chunked -> supertile L2 reuse.
// Staging: global_load_lds width-16, 16B chunks XOR-swizzled on BOTH sides.
// MODE: 0 plain, 1 +bias, 2 silu(v+bias), 3 +resid, 4 silu(g)*v (g pair)
// QKV: blockIdx.z selects Q/K/V; V is written TRANSPOSED to [b*h][d][T].
template<int MODE, bool OUT_SPLIT, bool QKV>
__global__ __launch_bounds__(256) void gemm2_kernel(
    const _Float16* __restrict__ Ahi, const _Float16* __restrict__ Alo,
    const _Float16* __restrict__ Bhi, const _Float16* __restrict__ Blo,
    const float* __restrict__ b0, const float* __restrict__ b1,
    const float* __restrict__ b2, const float* __restrict__ resid,
    const _Float16* __restrict__ ghi, const _Float16* __restrict__ glo,
    void* __restrict__ C1, void* __restrict__ C2,
    int M, int N, int K) {
  // grouped + XCD-chunked tile order (nbm always a multiple of 8 here)
  const int nbn = gridDim.x, nbm = gridDim.y;
  int bid = blockIdx.y * nbn + blockIdx.x;
  bid = (bid & 7) * ((nbn * nbm) >> 3) + (bid >> 3);   // XCD chunking
  const int nig = nbn << 3;
  const int gid = bid / nig, rem = bid - gid * nig;
  const int by = (gid << 3) + (rem & 7);
  const int bx = rem >> 3;
  int sel = 0;
  const float* bias = b0;
  size_t cbase = 0, bwoff = 0;
  if (QKV) {
    sel = blockIdx.z;
    bias = (sel == 0) ? b0 : ((sel == 1) ? b1 : b2);
    bwoff = (size_t)sel * D_MODEL * D_MODEL;
    cbase = (size_t)sel * (size_t)NTOK * D_MODEL;
  }
  const int n0 = bx * 128, m0 = by * 128;
  const int tid = threadIdx.x, lane = tid & 63, wv = tid >> 6;
  const int wr = wv >> 1, wc = wv & 1;
  const int l16 = lane & 15, lg = lane >> 4;
  // [buf][arr][128][32] halves; arr: 0=Ah 1=Al 2=Bh 3=Bl
  __shared__ _Float16 SH[2 * 4 * 128 * 32];
  f32x4 acc1[4][4], acc2[4][4];
  #pragma unroll
  for (int i = 0; i < 4; ++i)
    #pragma unroll
    for (int j = 0; j < 4; ++j) { acc1[i][j] = zero4(); acc2[i][j] = zero4(); }
  // staging: wave wv covers rows [wv*32, wv*32+32); 2 issues of 16 rows/array.
  const int srow = wv * 32 + (lane >> 2);
  const int scol = ((lane & 3) ^ ((lane >> 2) & 3)) * 8;
  const _Float16* ga0  = Ahi + (size_t)(m0 + srow) * K + scol;
  const _Float16* ga1  = ga0 + (size_t)16 * K;
  const _Float16* gal0 = Alo + (size_t)(m0 + srow) * K + scol;
  const _Float16* gal1 = gal0 + (size_t)16 * K;
  const _Float16* gb0  = Bhi + bwoff + (size_t)(n0 + srow) * K + scol;
  const _Float16* gb1  = gb0 + (size_t)16 * K;
  const _Float16* gbl0 = Blo + bwoff + (size_t)(n0 + srow) * K + scol;
  const _Float16* gbl1 = gbl0 + (size_t)16 * K;
  const int dbase = wv * 32 * 32;          // element offset within array
  const int csw = (lg ^ (l16 & 3)) * 8;    // swizzled read chunk offset

  #define STAGE(buf, kk) do {                                   \
    _Float16* sb = SH + (buf) * 16384;                          \
    gload16(ga0  + (kk), sb          + dbase);                  \
    gload16(ga1  + (kk), sb          + dbase + 512);            \
    gload16(gal0 + (kk), sb + 4096  + dbase);                   \
    gload16(gal1 + (kk), sb + 4096  + dbase + 512);             \
    gload16(gb0  + (kk), sb + 8192  + dbase);                   \
    gload16(gb1  + (kk), sb + 8192  + dbase + 512);             \
    gload16(gbl0 + (kk), sb + 12288 + dbase);                   \
    gload16(gbl1 + (kk), sb + 12288 + dbase + 512);             \
  } while (0)

  int cur = 0;
  STAGE(0, 0);
  __syncthreads();
  for (int kk = 0; kk < K; kk += 32) {
    if (kk + 32 < K) STAGE(cur ^ 1, kk + 32);   // prefetch next step
    const _Float16* sb = SH + cur * 16384;
    f16x8 af_h[4], af_l[4];
    #pragma unroll
    for (int i = 0; i < 4; ++i) {
      const int off = (wr*64 + i*16 + l16) * 32 + csw;
      af_h[i] = ld8h(sb + off);
      af_l[i] = ld8h(sb + 4096 + off);
    }
    #pragma unroll
    for (int j = 0; j < 4; ++j) {
      const int offb = (wc*64 + j*16 + l16) * 32 + csw;
      f16x8 bh = ld8h(sb + 8192 + offb);
      f16x8 bl = ld8h(sb + 12288 + offb);
      #pragma unroll
      for (int i = 0; i < 4; ++i) {
        acc1[i][j] = mfma16h(af_h[i], bh, acc1[i][j]);
        acc2[i][j] = mfma16h(af_h[i], bl, acc2[i][j]);
        acc2[i][j] = mfma16h(af_l[i], bh, acc2[i][j]);
      }
    }
    __syncthreads();   // drains prefetch vmcnt + publishes buf^1
    cur ^= 1;
  }
  #undef STAGE
  #pragma unroll
  for (int i = 0; i < 4; ++i) {
    const int row0 = m0 + wr*64 + i*16 + lg*4;   // D: row=(lane>>4)*4+t, col=lane&15
    #pragma unroll
    for (int j = 0; j < 4; ++j) {
      const int col = n0 + wc*64 + j*16 + l16;
      float bv = (MODE == 1 || MODE == 2) ? bias[col] : 0.f;
      #pragma unroll
      for (int t = 0; t < 4; ++t) {
        const int row = row0 + t;
        size_t idx;
        if (QKV && sel == 2)   // V -> transposed [b*h][d][T] layout
          idx = cbase + (size_t)(row >> 11) * ((size_t)D_MODEL * T_SEQ)
                      + (size_t)col * T_SEQ + (row & (T_SEQ - 1));
        else
          idx = cbase + (size_t)row * N + col;
        float v = acc1[i][j][t] + acc2[i][j][t] * RLOI + bv;
        if (MODE == 2) v = v / (1.f + __expf(-v));
        if (MODE == 3) v += resid[idx];
        if (MODE == 4) {
          float g = (float)ghi[idx] + (float)glo[idx] * RLOI;
          v = g / (1.f + __expf(-g)) * v;
        }
        if (OUT_SPLIT) {
          _Float16 h, l; split1(v, h, l);
          ((_Float16*)C1)[idx] = h;
          ((_Float16*)C2)[idx] = l;
        } else {
          ((float*)C1)[idx] = v;
        }
      }
    }
  }
}

// ---- RoPE (neox), in place on f16 pairs; one token-row per block ----
__global__ __launch_bounds__(256) void rope_kernel(_Float16* __restrict__ Qh,
                                                   _Float16* __restrict__ Ql,
                                                   _Float16* __restrict__ Kh,
                                                   _Float16* __restrict__ Kl) {
  const int row = blockIdx.x;
  const int tpos = row & (T_SEQ - 1);
  __shared__ float svs[64], cvs[64];
  if (threadIdx.x < 64) {
    double invf = exp(-(double)threadIdx.x * (9.210340371976184 / 64.0));
    double ph = fmod((double)tpos * invf, 6.283185307179586476925);
    sincosf((float)ph, &svs[threadIdx.x], &cvs[threadIdx.x]);
  }
  __syncthreads();
  for (int item = threadIdx.x; item < NHEAD * 64; item += 256) {
    const int h = item >> 6, d = item & 63;
    const float sv = svs[d], cv = cvs[d];
    const size_t i0 = (size_t)row * D_MODEL + h*HDIM + d;
    const size_t i1 = i0 + 64;
    float q0 = (float)Qh[i0] + (float)Ql[i0]*RLOI;
    float q1 = (float)Qh[i1] + (float)Ql[i1]*RLOI;
    float k0 = (float)Kh[i0] + (float)Kl[i0]*RLOI;
    float k1 = (float)Kh[i1] + (float)Kl[i1]*RLOI;
    _Float16 hh, ll;
    split1(q0*cv - q1*sv, hh, ll); Qh[i0]=hh; Ql[i0]=ll;
    split1(q1*cv + q0*sv, hh, ll); Qh[i1]=hh; Ql[i1]=ll;
    split1(k0*cv - k1*sv, hh, ll); Kh[i0]=hh; Kl[i0]=ll;
    split1(k1*cv + k0*sv, hh, ll); Kh[i1]=hh; Kl[i1]=ll;
  }
}

// ---- flash attention on pairs: 64 q-rows/block, KV tiles of 32 ----
// R7-EXACT revert (483us proven): K staged via global_load_lds into [32][128]
// with chunk^(row&7) XOR swizzle (source + ds_read side); V pre-transposed in
// global ([b*h][d][T]) and DMA-staged linearly into [128][32]. Softmax uses
// LIBCALL expf intentionally: R8-R11 measured that inlined __expf stretches
// live ranges -> 132-136 VGPR -> occupancy cliff (11%->6.3%) -> +110-137us.
// The libcall's call-clobber discipline keeps VGPR at 124 / 3 blocks per CU.
__global__ __launch_bounds__(256) void attn_kernel(
    const _Float16* __restrict__ Qh, const _Float16* __restrict__ Ql,
    const _Float16* __restrict__ Kh, const _Float16* __restrict__ Kl,
    const _Float16* __restrict__ VTh, const _Float16* __restrict__ VTl,
    _Float16* __restrict__ Oh, _Float16* __restrict__ Ol) {
  const int qb = (int)gridDim.x - 1 - (int)blockIdx.x;  // heavy blocks first
  const int bhid = blockIdx.y;
  const int b = bhid >> 4, h = bhid & 15;
  const int tid = threadIdx.x, lane = tid & 63, w = tid >> 6;
  const int l16 = lane & 15, lg = lane >> 4;
  __shared__ _Float16 Ksh[32][128], Ksl[32][128];
  __shared__ _Float16 Vth[128][32], Vtl[128][32];
  __shared__ _Float16 Psh[4][16][40], Psl[4][16][40];
  const size_t hbase  = (size_t)b * T_SEQ * D_MODEL + (size_t)h * HDIM;
  const size_t vtbase = (size_t)bhid * (size_t)HDIM * T_SEQ;
  const size_t qrow0 = (size_t)qb * 64;

  f16x8 qf_h[4], qf_l[4];
  {
    const size_t qoff = hbase + (qrow0 + w*16 + l16) * D_MODEL + lg*8;
    #pragma unroll
    for (int c = 0; c < 4; ++c) {
      qf_h[c] = ld8h(Qh + qoff + c*32);
      qf_l[c] = ld8h(Ql + qoff + c*32);
    }
  }
  f32x4 acc1[8], acc2[8];
  #pragma unroll
  for (int df = 0; df < 8; ++df) { acc1[df] = zero4(); acc2[df] = zero4(); }
  float mrow[4] = {-3e38f,-3e38f,-3e38f,-3e38f};
  float drow[4] = {0.f,0.f,0.f,0.f};

  // staging pointers (DMA; K source chunk-XOR-swizzled, V^T linear)
  const int krow = w*8 + (lane >> 4);
  const int kch0 = ((lane & 15) ^ (krow & 7)) * 8;
  const int kch1 = ((lane & 15) ^ ((krow + 4) & 7)) * 8;
  const _Float16* gkh0 = Kh + hbase + (size_t)krow * D_MODEL + kch0;
  const _Float16* gkh1 = Kh + hbase + (size_t)(krow + 4) * D_MODEL + kch1;
  const _Float16* gkl0 = Kl + hbase + (size_t)krow * D_MODEL + kch0;
  const _Float16* gkl1 = Kl + hbase + (size_t)(krow + 4) * D_MODEL + kch1;
  _Float16* dkh0 = &Ksh[w*8][0];   _Float16* dkh1 = &Ksh[w*8+4][0];
  _Float16* dkl0 = &Ksl[w*8][0];   _Float16* dkl1 = &Ksl[w*8+4][0];
  const int vrow = w*32 + (lane >> 2);
  const int vcol = (lane & 3) * 8;
  const _Float16* gvh0 = VTh + vtbase + (size_t)vrow * T_SEQ + vcol;
  const _Float16* gvh1 = gvh0 + (size_t)16 * T_SEQ;
  const _Float16* gvl0 = VTl + vtbase + (size_t)vrow * T_SEQ + vcol;
  const _Float16* gvl1 = gvl0 + (size_t)16 * T_SEQ;
  _Float16* dvh0 = &Vth[w*32][0];  _Float16* dvh1 = &Vth[w*32+16][0];
  _Float16* dvl0 = &Vtl[w*32][0];  _Float16* dvl1 = &Vtl[w*32+16][0];

  const int nkb = (qb + 1) * 2;
  const float scale = 0.088388347648318447f;  // 1/sqrt(128)

  for (int kb = 0; kb < nkb; ++kb) {
    __syncthreads();
    const size_t ko = (size_t)kb * 32 * D_MODEL;
    const size_t vo = (size_t)kb * 32;
    gload16(gkh0 + ko, dkh0);  gload16(gkh1 + ko, dkh1);
    gload16(gkl0 + ko, dkl0);  gload16(gkl1 + ko, dkl1);
    gload16(gvh0 + vo, dvh0);  gload16(gvh1 + vo, dvh1);
    gload16(gvl0 + vo, dvl0);  gload16(gvl1 + vo, dvl1);
    __syncthreads();

    f32x4 s0 = zero4(), s0x = zero4(), s1 = zero4(), s1x = zero4();
    #pragma unroll
    for (int c = 0; c < 4; ++c) {
      const int pk = ((4*c + lg) ^ (l16 & 7)) * 8;
      f16x8 kh0 = ld8h(&Ksh[l16][pk]);
      f16x8 kl0 = ld8h(&Ksl[l16][pk]);
      f16x8 kh1 = ld8h(&Ksh[16 + l16][pk]);
      f16x8 kl1 = ld8h(&Ksl[16 + l16][pk]);
      s0  = mfma16h(qf_h[c], kh0, s0);
      s0x = mfma16h(qf_h[c], kl0, s0x);
      s0x = mfma16h(qf_l[c], kh0, s0x);
      s1  = mfma16h(qf_h[c], kh1, s1);
      s1x = mfma16h(qf_h[c], kl1, s1x);
      s1x = mfma16h(qf_l[c], kh1, s1x);
    }

    float p0[4], p1[4], corrv[4];
    #pragma unroll
    for (int t = 0; t < 4; ++t) {
      int qrow = qb*64 + w*16 + lg*4 + t;
      float a  = (s0[t] + s0x[t] * RLOI) * scale;
      float bb = (s1[t] + s1x[t] * RLOI) * scale;
      if (kb*32      + l16 > qrow) a  = -1e9f;
      if (kb*32 + 16 + l16 > qrow) bb = -1e9f;
      float mx = fmaxf(a, bb);
      #pragma unroll
      for (int d = 1; d < 16; d <<= 1) mx = fmaxf(mx, __shfl_xor(mx, d, 64));
      float mnew = fmaxf(mrow[t], mx);
      float corr = expf(mrow[t] - mnew);
      float e0 = expf(a - mnew), e1 = expf(bb - mnew);
      float ps = e0 + e1;
      #pragma unroll
      for (int d = 1; d < 16; d <<= 1) ps += __shfl_xor(ps, d, 64);
      drow[t] = drow[t] * corr + ps;
      mrow[t] = mnew;
      corrv[t] = corr;
      p0[t] = e0; p1[t] = e1;
    }
    #pragma unroll
    for (int df = 0; df < 8; ++df)
      #pragma unroll
      for (int t = 0; t < 4; ++t) { acc1[df][t] *= corrv[t]; acc2[df][t] *= corrv[t]; }

    // P (D-layout) -> per-wave LDS -> reload in A-frag layout (split pair).
    #pragma unroll
    for (int t = 0; t < 4; ++t) {
      _Float16 hh, ll;
      split1(p0[t], hh, ll);
      Psh[w][lg*4 + t][l16] = hh;  Psl[w][lg*4 + t][l16] = ll;
      split1(p1[t], hh, ll);
      Psh[w][lg*4 + t][16 + l16] = hh;  Psl[w][lg*4 + t][16 + l16] = ll;
    }
    asm volatile("s_waitcnt lgkmcnt(0)" ::: "memory");
    __builtin_amdgcn_sched_barrier(0);
    f16x8 pf_h = ld8h(&Psh[w][l16][lg*8]);
    f16x8 pf_l = ld8h(&Psl[w][l16][lg*8]);
    #pragma unroll
    for (int df = 0; df < 8; ++df) {
      f16x8 vh = ld8h(&Vth[df*16 + l16][lg*8]);
      f16x8 vl = ld8h(&Vtl[df*16 + l16][lg*8]);
      acc1[df] = mfma16h(pf_h, vh, acc1[df]);
      acc2[df] = mfma16h(pf_h, vl, acc2[df]);
      acc2[df] = mfma16h(pf_l, vh, acc2[df]);
    }
  }
  #pragma unroll
  for (int df = 0; df < 8; ++df)
    #pragma unroll
    for (int t = 0; t < 4; ++t) {
      float o = (acc1[df][t] + acc2[df][t] * RLOI) / drow[t];
      _Float16 hh, ll; split1(o, hh, ll);
      const size_t oo = hbase + (qrow0 + w*16 + lg*4 + t) * D_MODEL + df*16 + l16;
      Oh[oo] = hh; Ol[oo] = ll;
    }
}

// ---- prev pair: t==0 ? 0 : split(x_post[b,t-1,:]) ----
__global__ __launch_bounds__(256) void shiftprev_kernel(const float* __restrict__ xpost,
                                                        _Float16* __restrict__ ph,
                                                        _Float16* __restrict__ pl) {
  const int row = blockIdx.x;
  const int tpos = row & (T_SEQ - 1);
  const size_t o = (size_t)row * D_MODEL + threadIdx.x * 8;
  f16x8 hh, ll;
  if (tpos == 0) {
    #pragma unroll
    for (int i = 0; i < 8; ++i) { hh[i] = (_Float16)0.f; ll[i] = (_Float16)0.f; }
  } else {
    const float* src = xpost + o - D_MODEL;
    #pragma unroll
    for (int i = 0; i < 8; ++i) {
      _Float16 h, l; split1(src[i], h, l); hh[i] = h; ll[i] = l;
    }
  }
  *(f16x8*)(ph + o) = hh;
  *(f16x8*)(pl + o) = ll;
}

// ---- per-row err = mean_D (pred - (xpost - xorig))^2 ----
__global__ __launch_bounds__(256) void err_kernel(const float* __restrict__ pred,
                                                  const float* __restrict__ xpost,
                                                  const float* __restrict__ xorig,
                                                  float* __restrict__ err) {
  const int row = blockIdx.x, tid = threadIdx.x;
  const size_t base = (size_t)row * D_MODEL + tid * 8;
  const float* pp = pred + base;
  const float* ap = xpost + base;
  const float* op = xorig + base;
  float ss = 0.f;
  #pragma unroll
  for (int i = 0; i < 8; ++i) {
    float d = pp[i] - (ap[i] - op[i]);
    ss += d * d;
  }
  ss = wredsum(ss);
  __shared__ float red[4];
  if ((tid & 63) == 0) red[tid >> 6] = ss;
  __syncthreads();
  if (tid == 0) err[row] = (red[0]+red[1]+red[2]+red[3]) / (float)D_MODEL;
}

// ---- stats: mean/std of err -> tpn_loss, g_continuous, binary_targets ----
__global__ __launch_bounds__(1024) void stats_kernel(const float* __restrict__ err,
                                                     float* __restrict__ dout) {
  __shared__ float red[16];
  __shared__ float sh[2];
  const int tid = threadIdx.x;
  float s = 0.f;
  for (int i = tid; i < NTOK; i += 1024) s += err[i];
  s = wredsum(s);
  if ((tid & 63) == 0) red[tid >> 6] = s;
  __syncthreads();
  if (tid == 0) {
    float t = 0.f;
    for (int i = 0; i < 16; ++i) t += red[i];
    sh[0] = t / (float)NTOK;
  }
  __syncthreads();
  const float mean = sh[0];
  float v = 0.f;
  for (int i = tid; i < NTOK; i += 1024) { float d = err[i] - mean; v += d * d; }
  v = wredsum(v);
  __syncthreads();
  if ((tid & 63) == 0) red[tid >> 6] = v;
  __syncthreads();
  if (tid == 0) {
    float t = 0.f;
    for (int i = 0; i < 16; ++i) t += red[i];
    sh[1] = sqrtf(t / (float)NTOK);
    dout[OFF_TPN] = mean;   // tpn_loss == mean(err)
  }
  __syncthreads();
  const float stdv = sh[1];
  for (int i = tid; i < NTOK; i += 1024) {
    float z = (err[i] - mean) / (stdv + 1e-6f);
    dout[OFF_G + i] = 1.f / (1.f + expf(-z));
    dout[OFF_B + i] = (err[i] > mean) ? 1.f : 0.f;
  }
}

// ---- causal router scores/probs ----
__global__ __launch_bounds__(256) void cscore_kernel(const float* __restrict__ x,
                                                     const float* __restrict__ rwv,
                                                     const float* __restrict__ rbv,
                                                     float* __restrict__ cs,
                                                     float* __restrict__ probs) {
  const int row = blockIdx.x, tid = threadIdx.x;
  const float* xr = x + (size_t)row * D_MODEL + tid * 8;
  const float* wr = rwv + tid * 8;
  float s = 0.f;
  #pragma unroll
  for (int i = 0; i < 8; ++i) s += xr[i] * wr[i];
  s = wredsum(s);
  __shared__ float red[4];
  if ((tid & 63) == 0) red[tid >> 6] = s;
  __syncthreads();
  if (tid == 0) {
    float v = red[0]+red[1]+red[2]+red[3] + rbv[0];
    cs[row] = v;
    probs[row] = 1.f / (1.f + expf(-v));
  }
}

// ---- BCE-with-logits ----
__global__ __launch_bounds__(1024) void closs_kernel(const float* __restrict__ cs,
                                                     const float* __restrict__ tgt,
                                                     float* __restrict__ outv) {
  __shared__ float red[16];
  const int tid = threadIdx.x;
  float a = 0.f;
  for (int i = tid; i < NTOK; i += 1024) {
    float s = cs[i], t = tgt[i];
    a += fmaxf(s, 0.f) - s * t + log1pf(expf(-fabsf(s)));
  }
  a = wredsum(a);
  if ((tid & 63) == 0) red[tid >> 6] = a;
  __syncthreads();
  if (tid == 0) {
    float t = 0.f;
    for (int i = 0; i < 16; ++i) t += red[i];
    outv[0] = t / (float)NTOK;
  }
}

extern "C" void kernel_launch(void* const* d_in, const int* in_sizes, int n_in,
                              void* d_out, int out_size, void* d_ws, size_t ws_size,
                              hipStream_t stream) {
  (void)in_sizes; (void)n_in; (void)out_size; (void)ws_size;
  const float* x_in = (const float*)d_in[0];
  const float* q_w  = (const float*)d_in[1];
  const float* q_b  = (const float*)d_in[2];
  const float* k_w  = (const float*)d_in[3];
  const float* k_b  = (const float*)d_in[4];
  const float* v_w  = (const float*)d_in[5];
  const float* v_b  = (const float*)d_in[6];
  const float* o_w  = (const float*)d_in[7];
  const float* ln1  = (const float*)d_in[8];
  const float* ln2  = (const float*)d_in[9];
  const float* gw   = (const float*)d_in[10];
  const float* uw   = (const float*)d_in[11];
  const float* dw   = (const float*)d_in[12];
  const float* t1w  = (const float*)d_in[13];
  const float* t1b  = (const float*)d_in[14];
  const float* t2w  = (const float*)d_in[15];
  const float* t2b  = (const float*)d_in[16];
  const float* rw   = (const float*)d_in[17];
  const float* rb   = (const float*)d_in[18];
  float* out = (float*)d_out;
  char* ws = (char*)d_ws;

  // -------- workspace plan, peak 208 MiB (proven-safe envelope) --------
  _Float16* WQKVh = (_Float16*)(ws + 0);           // 3x [2048][2048]
  _Float16* WQKVl = (_Float16*)(ws + 25165824);
  _Float16* WOh   = (_Float16*)(ws + 0);
  _Float16* WOl   = (_Float16*)(ws + 8388608);
  _Float16* WDh   = (_Float16*)(ws + 0);           // [2048][4096] half
  _Float16* WDl   = (_Float16*)(ws + 16777216);
  _Float16* WT1h  = (_Float16*)(ws + 0);
  _Float16* WT1l  = (_Float16*)(ws + 8388608);
  _Float16* WT2h  = (_Float16*)(ws + 16777216);
  _Float16* WT2l  = (_Float16*)(ws + 25165824);
  _Float16* Hh    = (_Float16*)(ws + 50331648);
  _Float16* Hl    = (_Float16*)(ws + 67108864);
  _Float16* PREVh = Hh;
  _Float16* PREVl = Hl;
  _Float16* QKVh  = (_Float16*)(ws + 83886080);    // [3][4096][2048]; V part is VT
  _Float16* QKVl  = (_Float16*)(ws + 134217728);
  _Float16* CTXh  = (_Float16*)(ws + 184549376);
  _Float16* CTXl  = (_Float16*)(ws + 201326592);   // ends 218103808 (208 MiB)
  _Float16* WGh   = (_Float16*)(ws + 83886080);    // [4096][2048] half
  _Float16* WGl   = (_Float16*)(ws + 100663296);
  _Float16* WUh   = (_Float16*)(ws + 117440512);
  _Float16* WUl   = (_Float16*)(ws + 134217728);
  _Float16* MLPh  = (_Float16*)(ws + 150994944);   // [4096][4096] half
  _Float16* MLPl  = (_Float16*)(ws + 184549376);   // ends 218103808
  _Float16* A1h   = (_Float16*)(ws + 83886080);
  _Float16* A1l   = (_Float16*)(ws + 100663296);
  float*    PREDf = (float*)   (ws + 117440512);   // 32 MiB, ends 150994944
  float*    ERRf  = (float*)   (ws + 150994944);
  float*    CSf   = (float*)   (ws + 151011328);

  const size_t DD = (size_t)D_MODEL * D_MODEL;
  const size_t TD = (size_t)NTOK * D_MODEL;
  dim3 tb(32, 8);
  const dim3 gW22(64, 64);     // [2048]x[2048] split
  const dim3 gWg(128, 64);     // gw/uw half: C=4096, R=2048
  const dim3 gWd(64, 128);     // dw half:    C=2048, R=4096

  // 1) QKV weights -> A
  wsplit_kernel<<<gW22, tb, 0, stream>>>(q_w, WQKVh,        WQKVl,        D_MODEL, 0, 0, D_MODEL);
  wsplit_kernel<<<gW22, tb, 0, stream>>>(k_w, WQKVh + DD,   WQKVl + DD,   D_MODEL, 0, 0, D_MODEL);
  wsplit_kernel<<<gW22, tb, 0, stream>>>(v_w, WQKVh + 2*DD, WQKVl + 2*DD, D_MODEL, 0, 0, D_MODEL);
  // 2) h = rmsnorm(x, ln1) -> B
  rmsnorm_kernel<<<NTOK, 256, 0, stream>>>(x_in, ln1, Hh, Hl);
  // 3) fused QKV GEMM -> C (z selects Q/K/V; V written transposed [b*h][d][T])
  gemm2_kernel<1,true,true><<<dim3(16,32,3),256,0,stream>>>(
      Hh, Hl, WQKVh, WQKVl, q_b, k_b, v_b, nullptr, nullptr, nullptr,
      QKVh, QKVl, NTOK, D_MODEL, D_MODEL);
  // 4) RoPE in place on Q,K
  rope_kernel<<<NTOK, 256, 0, stream>>>(QKVh, QKVl, QKVh + TD, QKVl + TD);
  // 5) attention -> D (CTX)
  attn_kernel<<<dim3(T_SEQ/64, B_SZ*NHEAD), 256, 0, stream>>>(
      QKVh, QKVl, QKVh + TD, QKVl + TD, QKVh + 2*TD, QKVl + 2*TD, CTXh, CTXl);
  // 6) o_w -> A; x = x_in + ctx @ o_w -> out
  wsplit_kernel<<<gW22, tb, 0, stream>>>(o_w, WOh, WOl, D_MODEL, 0, 0, D_MODEL);
  gemm2_kernel<3,false,false><<<dim3(16,32),256,0,stream>>>(
      CTXh, CTXl, WOh, WOl, nullptr, nullptr, nullptr, x_in, nullptr, nullptr,
      out, nullptr, NTOK, D_MODEL, D_MODEL);
  // 7) h2 = rmsnorm(x, ln2) -> B
  rmsnorm_kernel<<<NTOK, 256, 0, stream>>>(out, ln2, Hh, Hl);
  // 8) FFN in two halves of F; down accumulates into out (split-K, fp32)
  for (int half = 0; half < 2; ++half) {
    const int f0 = half * (FFN/2);
    wsplit_kernel<<<gWg, tb, 0, stream>>>(gw, WGh, WGl, FFN, 0, f0, D_MODEL);
    wsplit_kernel<<<gWg, tb, 0, stream>>>(uw, WUh, WUl, FFN, 0, f0, D_MODEL);
    gemm2_kernel<0,true,false><<<dim3(32,32),256,0,stream>>>(
        Hh, Hl, WGh, WGl, nullptr, nullptr, nullptr, nullptr, nullptr, nullptr,
        MLPh, MLPl, NTOK, FFN/2, D_MODEL);
    gemm2_kernel<4,true,false><<<dim3(32,32),256,0,stream>>>(
        Hh, Hl, WUh, WUl, nullptr, nullptr, nullptr, nullptr, MLPh, MLPl,
        MLPh, MLPl, NTOK, FFN/2, D_MODEL);
    wsplit_kernel<<<gWd, tb, 0, stream>>>(dw, WDh, WDl, D_MODEL, f0, 0, FFN/2);
    gemm2_kernel<3,false,false><<<dim3(16,32),256,0,stream>>>(
        MLPh, MLPl, WDh, WDl, nullptr, nullptr, nullptr, out, nullptr, nullptr,
        out, nullptr, NTOK, D_MODEL, FFN/2);
  }
  // 9) TPN
  shiftprev_kernel<<<NTOK, 256, 0, stream>>>(out, PREVh, PREVl);
  wsplit_kernel<<<gW22, tb, 0, stream>>>(t1w, WT1h, WT1l, D_MODEL, 0, 0, D_MODEL);
  wsplit_kernel<<<gW22, tb, 0, stream>>>(t2w, WT2h, WT2l, D_MODEL, 0, 0, D_MODEL);
  gemm2_kernel<2,true,false><<<dim3(16,32),256,0,stream>>>(
      PREVh, PREVl, WT1h, WT1l, t1b, nullptr, nullptr, nullptr, nullptr, nullptr,
      A1h, A1l, NTOK, D_MODEL, D_MODEL);
  gemm2_kernel<1,false,false><<<dim3(16,32),256,0,stream>>>(
      A1h, A1l, WT2h, WT2l, t2b, nullptr, nullptr, nullptr, nullptr, nullptr,
      PREDf, nullptr, NTOK, D_MODEL, D_MODEL);
  // 10) losses / routers
  err_kernel<<<NTOK, 256, 0, stream>>>(PREDf, out, x_in, ERRf);
  stats_kernel<<<1, 1024, 0, stream>>>(ERRf, out);
  cscore_kernel<<<NTOK, 256, 0, stream>>>(x_in, rw, rb, CSf, out + OFF_CP);
  closs_kernel<<<1, 1024, 0, stream>>>(CSf, out + OFF_B, out + OFF_CL);
}